// Round 1
// baseline (979.669 us; speedup 1.0000x reference)
//
#include <hip/hip_runtime.h>

#define BB 2048
#define TT 256
#define DA 20
#define DZ 4
#define KK 3

// symmetric 4x4 stored as 10 floats, upper-tri row-major:
// [0]=00 [1]=01 [2]=02 [3]=03 [4]=11 [5]=12 [6]=13 [7]=22 [8]=23 [9]=33
__device__ __forceinline__ void sym_expand(const float* s, float* f){
  f[0]=s[0];  f[1]=s[1];  f[2]=s[2];  f[3]=s[3];
  f[4]=s[1];  f[5]=s[4];  f[6]=s[5];  f[7]=s[6];
  f[8]=s[2];  f[9]=s[5];  f[10]=s[7]; f[11]=s[8];
  f[12]=s[3]; f[13]=s[6]; f[14]=s[8]; f[15]=s[9];
}

// general 4x4 inverse via 2x2 subdeterminants (row-major)
__device__ __forceinline__ void inv4(const float* m, float* b){
  float s0 = m[0]*m[5]  - m[4]*m[1];
  float s1 = m[0]*m[6]  - m[4]*m[2];
  float s2 = m[0]*m[7]  - m[4]*m[3];
  float s3 = m[1]*m[6]  - m[5]*m[2];
  float s4 = m[1]*m[7]  - m[5]*m[3];
  float s5 = m[2]*m[7]  - m[6]*m[3];
  float c5 = m[10]*m[15] - m[14]*m[11];
  float c4 = m[9]*m[15]  - m[13]*m[11];
  float c3 = m[9]*m[14]  - m[13]*m[10];
  float c2 = m[8]*m[15]  - m[12]*m[11];
  float c1 = m[8]*m[14]  - m[12]*m[10];
  float c0 = m[8]*m[13]  - m[12]*m[9];
  float det = s0*c5 - s1*c4 + s2*c3 + s3*c2 - s4*c1 + s5*c0;
  float id = 1.0f/det;
  b[0]  = ( m[5]*c5  - m[6]*c4  + m[7]*c3 )*id;
  b[1]  = (-m[1]*c5  + m[2]*c4  - m[3]*c3 )*id;
  b[2]  = ( m[13]*s5 - m[14]*s4 + m[15]*s3)*id;
  b[3]  = (-m[9]*s5  + m[10]*s4 - m[11]*s3)*id;
  b[4]  = (-m[4]*c5  + m[6]*c2  - m[7]*c1 )*id;
  b[5]  = ( m[0]*c5  - m[2]*c2  + m[3]*c1 )*id;
  b[6]  = (-m[12]*s5 + m[14]*s2 - m[15]*s1)*id;
  b[7]  = ( m[8]*s5  - m[10]*s2 + m[11]*s1)*id;
  b[8]  = ( m[4]*c4  - m[5]*c2  + m[7]*c0 )*id;
  b[9]  = (-m[0]*c4  + m[1]*c2  - m[3]*c0 )*id;
  b[10] = ( m[12]*s4 - m[13]*s2 + m[15]*s0)*id;
  b[11] = (-m[8]*s4  + m[9]*s2  - m[11]*s0)*id;
  b[12] = (-m[4]*c3  + m[5]*c1  - m[6]*c0 )*id;
  b[13] = ( m[0]*c3  - m[1]*c1  + m[2]*c0 )*id;
  b[14] = (-m[12]*s3 + m[13]*s1 - m[14]*s0)*id;
  b[15] = ( m[8]*s3  - m[9]*s1  + m[10]*s0)*id;
}

__device__ __forceinline__ void mm4(const float* A, const float* Bm, float* C){
  #pragma unroll
  for (int i=0;i<4;i++){
    #pragma unroll
    for (int j=0;j<4;j++){
      float acc = A[i*4+0]*Bm[0*4+j];
      acc = fmaf(A[i*4+1], Bm[1*4+j], acc);
      acc = fmaf(A[i*4+2], Bm[2*4+j], acc);
      acc = fmaf(A[i*4+3], Bm[3*4+j], acc);
      C[i*4+j] = acc;
    }
  }
}

// C = A * B^T
__device__ __forceinline__ void mm4_bt(const float* A, const float* Bm, float* C){
  #pragma unroll
  for (int i=0;i<4;i++){
    #pragma unroll
    for (int j=0;j<4;j++){
      float acc = A[i*4+0]*Bm[j*4+0];
      acc = fmaf(A[i*4+1], Bm[j*4+1], acc);
      acc = fmaf(A[i*4+2], Bm[j*4+2], acc);
      acc = fmaf(A[i*4+3], Bm[j*4+3], acc);
      C[i*4+j] = acc;
    }
  }
}

// Phase 1: per (b,t) compute A_mix (16), G' = C^T C / R (10 sym), w' = C^T a / R (4)
// SoA layout [t][comp][b] for coalesced access by the sequential kernel.
__global__ __launch_bounds__(256) void kvae_precompute(
    const float* __restrict__ a, const float* __restrict__ logits,
    const float* __restrict__ Abase, const float* __restrict__ Cbase,
    float* __restrict__ wsA, float* __restrict__ wsG, float* __restrict__ wsW)
{
  __shared__ float sA[KK*16];
  __shared__ float sC[KK*DA*DZ];
  for (int i = threadIdx.x; i < KK*16; i += 256) sA[i] = Abase[i];
  for (int i = threadIdx.x; i < KK*DA*DZ; i += 256) sC[i] = Cbase[i];
  __syncthreads();

  int tid = blockIdx.x*256 + threadIdx.x;
  int b = tid & (BB-1);
  int t = tid >> 11;   // BB = 2048 = 2^11

  const float* lg = logits + ((size_t)b*TT + t)*KK;
  float l0 = lg[0], l1 = lg[1], l2 = lg[2];
  float mx = fmaxf(l0, fmaxf(l1, l2));
  float e0 = expf(l0-mx), e1 = expf(l1-mx), e2 = expf(l2-mx);
  float is = 1.0f/(e0+e1+e2);
  float a0 = e0*is, a1 = e1*is, a2 = e2*is;

  float Am[16];
  #pragma unroll
  for (int c=0;c<16;c++) Am[c] = fmaf(a0, sA[c], fmaf(a1, sA[16+c], a2*sA[32+c]));

  const float* av = a + ((size_t)b*TT + t)*DA;
  float G[10] = {0,0,0,0,0,0,0,0,0,0};
  float w[4]  = {0,0,0,0};
  #pragma unroll
  for (int d=0; d<DA; d++){
    float ad = av[d];
    float c0 = fmaf(a0, sC[d*4+0], fmaf(a1, sC[80+d*4+0], a2*sC[160+d*4+0]));
    float c1 = fmaf(a0, sC[d*4+1], fmaf(a1, sC[80+d*4+1], a2*sC[160+d*4+1]));
    float c2 = fmaf(a0, sC[d*4+2], fmaf(a1, sC[80+d*4+2], a2*sC[160+d*4+2]));
    float c3 = fmaf(a0, sC[d*4+3], fmaf(a1, sC[80+d*4+3], a2*sC[160+d*4+3]));
    w[0] = fmaf(c0, ad, w[0]);
    w[1] = fmaf(c1, ad, w[1]);
    w[2] = fmaf(c2, ad, w[2]);
    w[3] = fmaf(c3, ad, w[3]);
    G[0] = fmaf(c0,c0,G[0]); G[1] = fmaf(c0,c1,G[1]); G[2] = fmaf(c0,c2,G[2]); G[3] = fmaf(c0,c3,G[3]);
    G[4] = fmaf(c1,c1,G[4]); G[5] = fmaf(c1,c2,G[5]); G[6] = fmaf(c1,c3,G[6]);
    G[7] = fmaf(c2,c2,G[7]); G[8] = fmaf(c2,c3,G[8]);
    G[9] = fmaf(c3,c3,G[9]);
  }
  const float invR = 1.0f/0.03f;
  #pragma unroll
  for (int c=0;c<16;c++) wsA[((size_t)t*16+c)*BB + b] = Am[c];
  #pragma unroll
  for (int c=0;c<10;c++) wsG[((size_t)t*10+c)*BB + b] = G[c]*invR;
  #pragma unroll
  for (int c=0;c<4;c++)  wsW[((size_t)t*4+c)*BB + b]  = w[c]*invR;
}

// Phase 2: one thread per batch element. Forward Kalman filter (information-form
// update via 4x4 Woodbury), then backward RTS smoother writing outputs.
__global__ __launch_bounds__(64) void kvae_seq(
    const float* __restrict__ wsA, const float* __restrict__ wsG, const float* __restrict__ wsW,
    float* __restrict__ wsZh, float* __restrict__ wsPc, float* __restrict__ wsPz, float* __restrict__ wsM,
    float* __restrict__ out)
{
  int b = blockIdx.x*64 + threadIdx.x;

  float z[4] = {0.f,0.f,0.f,0.f};
  float S[10] = {20.f,0.f,0.f,0.f, 20.f,0.f,0.f, 20.f,0.f, 20.f}; // 20*I

  // ---------------- forward filter ----------------
  for (int t=0; t<TT; ++t){
    float Am[16], G[10], w[4];
    #pragma unroll
    for (int c=0;c<16;c++) Am[c] = wsA[((size_t)t*16+c)*BB + b];
    #pragma unroll
    for (int c=0;c<10;c++) G[c]  = wsG[((size_t)t*10+c)*BB + b];
    #pragma unroll
    for (int c=0;c<4;c++)  w[c]  = wsW[((size_t)t*4+c)*BB + b];

    // z_hat = A z
    float zh[4];
    #pragma unroll
    for (int i=0;i<4;i++)
      zh[i] = fmaf(Am[i*4+3], z[3], fmaf(Am[i*4+2], z[2], fmaf(Am[i*4+1], z[1], Am[i*4+0]*z[0])));

    // P = A S A^T + 0.08 I   (unclamped std_hat)
    float Sf[16]; sym_expand(S, Sf);
    float AS[16]; mm4(Am, Sf, AS);
    float P[10];
    {
      int c=0;
      #pragma unroll
      for (int i=0;i<4;i++){
        #pragma unroll
        for (int j=0;j<4;j++){
          if (j < i) continue;
          float acc = AS[i*4+0]*Am[j*4+0];
          acc = fmaf(AS[i*4+1], Am[j*4+1], acc);
          acc = fmaf(AS[i*4+2], Am[j*4+2], acc);
          acc = fmaf(AS[i*4+3], Am[j*4+3], acc);
          if (i==j) acc += 0.08f;
          P[c++] = acc;
        }
      }
    }

    // M = (I + P G')^{-1} P   (== Joseph-form posterior covariance)
    float Pf[16]; sym_expand(P, Pf);
    float Gf[16]; sym_expand(G, Gf);
    float N[16]; mm4(Pf, Gf, N);
    N[0]+=1.f; N[5]+=1.f; N[10]+=1.f; N[15]+=1.f;
    float Ninv[16]; inv4(N, Ninv);
    float Mf[16]; mm4(Ninv, Pf, Mf);
    float M[10];
    {
      int c=0;
      #pragma unroll
      for (int i=0;i<4;i++){
        #pragma unroll
        for (int j=0;j<4;j++){
          if (j < i) continue;
          M[c++] = (i==j) ? Mf[i*4+j] : 0.5f*(Mf[i*4+j]+Mf[j*4+i]);
        }
      }
    }

    // post_z = z_hat + M (w' - G' z_hat)
    float u[4];
    #pragma unroll
    for (int i=0;i<4;i++)
      u[i] = w[i] - fmaf(Gf[i*4+3], zh[3], fmaf(Gf[i*4+2], zh[2], fmaf(Gf[i*4+1], zh[1], Gf[i*4+0]*zh[0])));
    float Ms[16]; sym_expand(M, Ms);
    float pz[4];
    #pragma unroll
    for (int i=0;i<4;i++)
      pz[i] = zh[i] + fmaf(Ms[i*4+3], u[3], fmaf(Ms[i*4+2], u[2], fmaf(Ms[i*4+1], u[1], Ms[i*4+0]*u[0])));

    // std_hat_c = elementwise max(P, 1e-4*I)  (off-diagonals clamped at 0!)
    float Pc[10];
    Pc[0]=fmaxf(P[0],1e-4f); Pc[1]=fmaxf(P[1],0.f);   Pc[2]=fmaxf(P[2],0.f);   Pc[3]=fmaxf(P[3],0.f);
    Pc[4]=fmaxf(P[4],1e-4f); Pc[5]=fmaxf(P[5],0.f);   Pc[6]=fmaxf(P[6],0.f);
    Pc[7]=fmaxf(P[7],1e-4f); Pc[8]=fmaxf(P[8],0.f);
    Pc[9]=fmaxf(P[9],1e-4f);

    #pragma unroll
    for (int c=0;c<4;c++)  wsZh[((size_t)t*4+c)*BB + b]  = zh[c];
    #pragma unroll
    for (int c=0;c<10;c++) wsPc[((size_t)t*10+c)*BB + b] = Pc[c];
    #pragma unroll
    for (int c=0;c<4;c++)  wsPz[((size_t)t*4+c)*BB + b]  = pz[c];
    #pragma unroll
    for (int c=0;c<10;c++) wsM[((size_t)t*10+c)*BB + b]  = M[c];

    #pragma unroll
    for (int c=0;c<4;c++)  z[c] = pz[c];
    #pragma unroll
    for (int c=0;c<10;c++) S[c] = M[c];
  }

  // ---------------- backward smoother ----------------
  const size_t Z0 = (size_t)BB*TT*DZ;
  float pzs[4], pss[10];
  #pragma unroll
  for (int c=0;c<4;c++)  pzs[c] = wsPz[((size_t)(TT-1)*4+c)*BB + b];
  #pragma unroll
  for (int c=0;c<10;c++) pss[c] = wsM[((size_t)(TT-1)*10+c)*BB + b];
  {
    size_t zo = ((size_t)b*TT + (TT-1))*DZ;
    #pragma unroll
    for (int c=0;c<4;c++) out[zo+c] = pzs[c];
    float pf[16]; sym_expand(pss, pf);
    size_t so = Z0 + ((size_t)b*TT + (TT-1))*16;
    #pragma unroll
    for (int c=0;c<16;c++) out[so+c] = pf[c];
  }

  for (int j=TT-2; j>=0; --j){
    float Pc1[10], A1[16], zh1[4], pzj[4], Mj[10];
    #pragma unroll
    for (int c=0;c<10;c++) Pc1[c] = wsPc[((size_t)(j+1)*10+c)*BB + b];
    #pragma unroll
    for (int c=0;c<16;c++) A1[c]  = wsA[((size_t)(j+1)*16+c)*BB + b];
    #pragma unroll
    for (int c=0;c<4;c++)  zh1[c] = wsZh[((size_t)(j+1)*4+c)*BB + b];
    #pragma unroll
    for (int c=0;c<4;c++)  pzj[c] = wsPz[((size_t)j*4+c)*BB + b];
    #pragma unroll
    for (int c=0;c<10;c++) Mj[c]  = wsM[((size_t)j*10+c)*BB + b];

    // D = M_j A_{j+1}^T inv(Pc_{j+1})
    float Pc1f[16]; sym_expand(Pc1, Pc1f);
    float E[16]; inv4(Pc1f, E);
    float Mjf[16]; sym_expand(Mj, Mjf);
    float Bm[16]; mm4_bt(Mjf, A1, Bm);
    float D[16]; mm4(Bm, E, D);

    // z_s = post_z_j + D (pz_s - z_hat_{j+1})
    float dz[4];
    #pragma unroll
    for (int k=0;k<4;k++) dz[k] = pzs[k]-zh1[k];
    float zs[4];
    #pragma unroll
    for (int i=0;i<4;i++)
      zs[i] = pzj[i] + fmaf(D[i*4+3], dz[3], fmaf(D[i*4+2], dz[2], fmaf(D[i*4+1], dz[1], D[i*4+0]*dz[0])));

    // s_s = M_j + D (ps_s - Pc_{j+1}) D^T
    float X[10];
    #pragma unroll
    for (int c=0;c<10;c++) X[c] = pss[c]-Pc1[c];
    float Xf[16]; sym_expand(X, Xf);
    float Y[16]; mm4(D, Xf, Y);
    float Ss[10];
    {
      int c=0;
      #pragma unroll
      for (int i=0;i<4;i++){
        #pragma unroll
        for (int j2=0;j2<4;j2++){
          if (j2 < i) continue;
          float acc = Y[i*4+0]*D[j2*4+0];
          acc = fmaf(Y[i*4+1], D[j2*4+1], acc);
          acc = fmaf(Y[i*4+2], D[j2*4+2], acc);
          acc = fmaf(Y[i*4+3], D[j2*4+3], acc);
          Ss[c] = Mj[c] + acc;
          c++;
        }
      }
    }

    size_t zo = ((size_t)b*TT + j)*DZ;
    #pragma unroll
    for (int c=0;c<4;c++) out[zo+c] = zs[c];
    float Ssf[16]; sym_expand(Ss, Ssf);
    size_t so = Z0 + ((size_t)b*TT + j)*16;
    #pragma unroll
    for (int c=0;c<16;c++) out[so+c] = Ssf[c];

    #pragma unroll
    for (int c=0;c<4;c++)  pzs[c] = zs[c];
    #pragma unroll
    for (int c=0;c<10;c++) pss[c] = Ss[c];
  }
}

extern "C" void kernel_launch(void* const* d_in, const int* in_sizes, int n_in,
                              void* d_out, int out_size, void* d_ws, size_t ws_size,
                              hipStream_t stream) {
  const float* a      = (const float*)d_in[0];
  const float* logits = (const float*)d_in[1];
  const float* Abase  = (const float*)d_in[2];
  const float* Cbase  = (const float*)d_in[3];
  float* out = (float*)d_out;
  float* ws  = (float*)d_ws;

  const size_t NT = (size_t)BB*TT;
  float* wsA  = ws;            // 16*NT
  float* wsG  = wsA + 16*NT;   // 10*NT
  float* wsW  = wsG + 10*NT;   // 4*NT
  float* wsZh = wsW + 4*NT;    // 4*NT
  float* wsPc = wsZh + 4*NT;   // 10*NT
  float* wsPz = wsPc + 10*NT;  // 4*NT
  float* wsM  = wsPz + 4*NT;   // 10*NT  (total 58*NT floats ~ 116 MB)

  kvae_precompute<<<dim3(BB*TT/256), dim3(256), 0, stream>>>(a, logits, Abase, Cbase, wsA, wsG, wsW);
  kvae_seq<<<dim3(BB/64), dim3(64), 0, stream>>>(wsA, wsG, wsW, wsZh, wsPc, wsPz, wsM, out);
}

// Round 2
// 710.789 us; speedup vs baseline: 1.3783x; 1.3783x over previous
//
#include <hip/hip_runtime.h>

#define BB 2048
#define TT 256
#define DA 20
#define DZ 4
#define KK 3
#define W1S 32   // ws1 floats per (t,b): A[16], G[10], w[4], pad[2]
#define W2S 24   // ws2 floats per (t,b): pz[4], Pc[10], M[10]

// symmetric 4x4 stored as 10 floats, upper-tri row-major:
// [0]=00 [1]=01 [2]=02 [3]=03 [4]=11 [5]=12 [6]=13 [7]=22 [8]=23 [9]=33
__device__ __forceinline__ void sym_expand(const float* s, float* f){
  f[0]=s[0];  f[1]=s[1];  f[2]=s[2];  f[3]=s[3];
  f[4]=s[1];  f[5]=s[4];  f[6]=s[5];  f[7]=s[6];
  f[8]=s[2];  f[9]=s[5];  f[10]=s[7]; f[11]=s[8];
  f[12]=s[3]; f[13]=s[6]; f[14]=s[8]; f[15]=s[9];
}

// general 4x4 inverse via 2x2 subdeterminants (row-major)
__device__ __forceinline__ void inv4(const float* m, float* b){
  float s0 = m[0]*m[5]  - m[4]*m[1];
  float s1 = m[0]*m[6]  - m[4]*m[2];
  float s2 = m[0]*m[7]  - m[4]*m[3];
  float s3 = m[1]*m[6]  - m[5]*m[2];
  float s4 = m[1]*m[7]  - m[5]*m[3];
  float s5 = m[2]*m[7]  - m[6]*m[3];
  float c5 = m[10]*m[15] - m[14]*m[11];
  float c4 = m[9]*m[15]  - m[13]*m[11];
  float c3 = m[9]*m[14]  - m[13]*m[10];
  float c2 = m[8]*m[15]  - m[12]*m[11];
  float c1 = m[8]*m[14]  - m[12]*m[10];
  float c0 = m[8]*m[13]  - m[12]*m[9];
  float det = s0*c5 - s1*c4 + s2*c3 + s3*c2 - s4*c1 + s5*c0;
  float id = 1.0f/det;
  b[0]  = ( m[5]*c5  - m[6]*c4  + m[7]*c3 )*id;
  b[1]  = (-m[1]*c5  + m[2]*c4  - m[3]*c3 )*id;
  b[2]  = ( m[13]*s5 - m[14]*s4 + m[15]*s3)*id;
  b[3]  = (-m[9]*s5  + m[10]*s4 - m[11]*s3)*id;
  b[4]  = (-m[4]*c5  + m[6]*c2  - m[7]*c1 )*id;
  b[5]  = ( m[0]*c5  - m[2]*c2  + m[3]*c1 )*id;
  b[6]  = (-m[12]*s5 + m[14]*s2 - m[15]*s1)*id;
  b[7]  = ( m[8]*s5  - m[10]*s2 + m[11]*s1)*id;
  b[8]  = ( m[4]*c4  - m[5]*c2  + m[7]*c0 )*id;
  b[9]  = (-m[0]*c4  + m[1]*c2  - m[3]*c0 )*id;
  b[10] = ( m[12]*s4 - m[13]*s2 + m[15]*s0)*id;
  b[11] = (-m[8]*s4  + m[9]*s2  - m[11]*s0)*id;
  b[12] = (-m[4]*c3  + m[5]*c1  - m[6]*c0 )*id;
  b[13] = ( m[0]*c3  - m[1]*c1  + m[2]*c0 )*id;
  b[14] = (-m[12]*s3 + m[13]*s1 - m[14]*s0)*id;
  b[15] = ( m[8]*s3  - m[9]*s1  + m[10]*s0)*id;
}

__device__ __forceinline__ void mm4(const float* A, const float* Bm, float* C){
  #pragma unroll
  for (int i=0;i<4;i++){
    #pragma unroll
    for (int j=0;j<4;j++){
      float acc = A[i*4+0]*Bm[0*4+j];
      acc = fmaf(A[i*4+1], Bm[1*4+j], acc);
      acc = fmaf(A[i*4+2], Bm[2*4+j], acc);
      acc = fmaf(A[i*4+3], Bm[3*4+j], acc);
      C[i*4+j] = acc;
    }
  }
}

// C = A * B^T
__device__ __forceinline__ void mm4_bt(const float* A, const float* Bm, float* C){
  #pragma unroll
  for (int i=0;i<4;i++){
    #pragma unroll
    for (int j=0;j<4;j++){
      float acc = A[i*4+0]*Bm[j*4+0];
      acc = fmaf(A[i*4+1], Bm[j*4+1], acc);
      acc = fmaf(A[i*4+2], Bm[j*4+2], acc);
      acc = fmaf(A[i*4+3], Bm[j*4+3], acc);
      C[i*4+j] = acc;
    }
  }
}

// ---------------- Phase 1: per (b,t) mixing + information-form stats ----------------
// ws1[t][b][32] = A_mix[16], G'=C^T C/R [10 sym], w'=C^T a/R [4], pad[2]
__global__ __launch_bounds__(256) void kvae_precompute(
    const float* __restrict__ a, const float* __restrict__ logits,
    const float* __restrict__ Abase, const float* __restrict__ Cbase,
    float* __restrict__ ws1)
{
  __shared__ float sA[KK*16];
  __shared__ float sC[KK*DA*DZ];
  for (int i = threadIdx.x; i < KK*16; i += 256) sA[i] = Abase[i];
  for (int i = threadIdx.x; i < KK*DA*DZ; i += 256) sC[i] = Cbase[i];
  __syncthreads();

  int tid = blockIdx.x*256 + threadIdx.x;
  int b = tid & (BB-1);
  int t = tid >> 11;   // BB = 2048 = 2^11

  const float* lg = logits + ((size_t)b*TT + t)*KK;
  float l0 = lg[0], l1 = lg[1], l2 = lg[2];
  float mx = fmaxf(l0, fmaxf(l1, l2));
  float e0 = expf(l0-mx), e1 = expf(l1-mx), e2 = expf(l2-mx);
  float is = 1.0f/(e0+e1+e2);
  float a0 = e0*is, a1 = e1*is, a2 = e2*is;

  float Am[16];
  #pragma unroll
  for (int c=0;c<16;c++) Am[c] = fmaf(a0, sA[c], fmaf(a1, sA[16+c], a2*sA[32+c]));

  // vectorized read of a[b][t][0..19] (80B, 16B-aligned)
  const float4* af = (const float4*)(a + ((size_t)b*TT + t)*DA);
  float4 av0=af[0], av1=af[1], av2=af[2], av3=af[3], av4=af[4];
  float av[20] = {av0.x,av0.y,av0.z,av0.w, av1.x,av1.y,av1.z,av1.w,
                  av2.x,av2.y,av2.z,av2.w, av3.x,av3.y,av3.z,av3.w,
                  av4.x,av4.y,av4.z,av4.w};

  float G[10] = {0,0,0,0,0,0,0,0,0,0};
  float w[4]  = {0,0,0,0};
  #pragma unroll
  for (int d=0; d<DA; d++){
    float ad = av[d];
    float c0 = fmaf(a0, sC[d*4+0], fmaf(a1, sC[80+d*4+0], a2*sC[160+d*4+0]));
    float c1 = fmaf(a0, sC[d*4+1], fmaf(a1, sC[80+d*4+1], a2*sC[160+d*4+1]));
    float c2 = fmaf(a0, sC[d*4+2], fmaf(a1, sC[80+d*4+2], a2*sC[160+d*4+2]));
    float c3 = fmaf(a0, sC[d*4+3], fmaf(a1, sC[80+d*4+3], a2*sC[160+d*4+3]));
    w[0] = fmaf(c0, ad, w[0]);
    w[1] = fmaf(c1, ad, w[1]);
    w[2] = fmaf(c2, ad, w[2]);
    w[3] = fmaf(c3, ad, w[3]);
    G[0] = fmaf(c0,c0,G[0]); G[1] = fmaf(c0,c1,G[1]); G[2] = fmaf(c0,c2,G[2]); G[3] = fmaf(c0,c3,G[3]);
    G[4] = fmaf(c1,c1,G[4]); G[5] = fmaf(c1,c2,G[5]); G[6] = fmaf(c1,c3,G[6]);
    G[7] = fmaf(c2,c2,G[7]); G[8] = fmaf(c2,c3,G[8]);
    G[9] = fmaf(c3,c3,G[9]);
  }
  const float invR = 1.0f/0.03f;
  #pragma unroll
  for (int c=0;c<10;c++) G[c] *= invR;
  #pragma unroll
  for (int c=0;c<4;c++)  w[c] *= invR;

  float4* dst = (float4*)(ws1 + ((size_t)t*BB + b)*W1S);
  dst[0] = make_float4(Am[0], Am[1], Am[2], Am[3]);
  dst[1] = make_float4(Am[4], Am[5], Am[6], Am[7]);
  dst[2] = make_float4(Am[8], Am[9], Am[10],Am[11]);
  dst[3] = make_float4(Am[12],Am[13],Am[14],Am[15]);
  dst[4] = make_float4(G[0], G[1], G[2], G[3]);
  dst[5] = make_float4(G[4], G[5], G[6], G[7]);
  dst[6] = make_float4(G[8], G[9], w[0], w[1]);
  dst[7] = make_float4(w[2], w[3], 0.f, 0.f);
}

// ---------------- Phase 2: sequential filter + smoother, 1 thread / batch ----------------

struct FIn { float4 q[8]; };
__device__ __forceinline__ void f_load(FIn& r, const float* __restrict__ ws1, int t, int b){
  const float4* p = (const float4*)(ws1 + ((size_t)t*BB + b)*W1S);
  #pragma unroll
  for (int i=0;i<8;i++) r.q[i] = p[i];
}

__device__ __forceinline__ void filt_step(const FIn& in, int t, int b,
    float* z, float* S, float* __restrict__ ws2)
{
  float Am[16] = {in.q[0].x,in.q[0].y,in.q[0].z,in.q[0].w,
                  in.q[1].x,in.q[1].y,in.q[1].z,in.q[1].w,
                  in.q[2].x,in.q[2].y,in.q[2].z,in.q[2].w,
                  in.q[3].x,in.q[3].y,in.q[3].z,in.q[3].w};
  float G[10]  = {in.q[4].x,in.q[4].y,in.q[4].z,in.q[4].w,
                  in.q[5].x,in.q[5].y,in.q[5].z,in.q[5].w,
                  in.q[6].x,in.q[6].y};
  float w[4]   = {in.q[6].z,in.q[6].w,in.q[7].x,in.q[7].y};

  // z_hat = A z
  float zh[4];
  #pragma unroll
  for (int i=0;i<4;i++)
    zh[i] = fmaf(Am[i*4+3], z[3], fmaf(Am[i*4+2], z[2], fmaf(Am[i*4+1], z[1], Am[i*4+0]*z[0])));

  // P = A S A^T + 0.08 I   (unclamped std_hat)
  float Sf[16]; sym_expand(S, Sf);
  float AS[16]; mm4(Am, Sf, AS);
  float P[10];
  {
    int c=0;
    #pragma unroll
    for (int i=0;i<4;i++){
      #pragma unroll
      for (int j=0;j<4;j++){
        if (j < i) continue;
        float acc = AS[i*4+0]*Am[j*4+0];
        acc = fmaf(AS[i*4+1], Am[j*4+1], acc);
        acc = fmaf(AS[i*4+2], Am[j*4+2], acc);
        acc = fmaf(AS[i*4+3], Am[j*4+3], acc);
        if (i==j) acc += 0.08f;
        P[c++] = acc;
      }
    }
  }

  // M = (I + P G')^{-1} P   (== Joseph-form posterior covariance)
  float Pf[16]; sym_expand(P, Pf);
  float Gf[16]; sym_expand(G, Gf);
  float N[16]; mm4(Pf, Gf, N);
  N[0]+=1.f; N[5]+=1.f; N[10]+=1.f; N[15]+=1.f;
  float Ninv[16]; inv4(N, Ninv);
  float Mf[16]; mm4(Ninv, Pf, Mf);
  float M[10];
  {
    int c=0;
    #pragma unroll
    for (int i=0;i<4;i++){
      #pragma unroll
      for (int j=0;j<4;j++){
        if (j < i) continue;
        M[c++] = (i==j) ? Mf[i*4+j] : 0.5f*(Mf[i*4+j]+Mf[j*4+i]);
      }
    }
  }

  // post_z = z_hat + M (w' - G' z_hat)
  float u[4];
  #pragma unroll
  for (int i=0;i<4;i++)
    u[i] = w[i] - fmaf(Gf[i*4+3], zh[3], fmaf(Gf[i*4+2], zh[2], fmaf(Gf[i*4+1], zh[1], Gf[i*4+0]*zh[0])));
  float Ms[16]; sym_expand(M, Ms);
  float pz[4];
  #pragma unroll
  for (int i=0;i<4;i++)
    pz[i] = zh[i] + fmaf(Ms[i*4+3], u[3], fmaf(Ms[i*4+2], u[2], fmaf(Ms[i*4+1], u[1], Ms[i*4+0]*u[0])));

  // std_hat_c = elementwise max(P, 1e-4*I)  (off-diagonals clamped at 0)
  float Pc[10];
  Pc[0]=fmaxf(P[0],1e-4f); Pc[1]=fmaxf(P[1],0.f);   Pc[2]=fmaxf(P[2],0.f);   Pc[3]=fmaxf(P[3],0.f);
  Pc[4]=fmaxf(P[4],1e-4f); Pc[5]=fmaxf(P[5],0.f);   Pc[6]=fmaxf(P[6],0.f);
  Pc[7]=fmaxf(P[7],1e-4f); Pc[8]=fmaxf(P[8],0.f);
  Pc[9]=fmaxf(P[9],1e-4f);

  float4* d = (float4*)(ws2 + ((size_t)t*BB + b)*W2S);
  d[0] = make_float4(pz[0],pz[1],pz[2],pz[3]);
  d[1] = make_float4(Pc[0],Pc[1],Pc[2],Pc[3]);
  d[2] = make_float4(Pc[4],Pc[5],Pc[6],Pc[7]);
  d[3] = make_float4(Pc[8],Pc[9],M[0],M[1]);
  d[4] = make_float4(M[2],M[3],M[4],M[5]);
  d[5] = make_float4(M[6],M[7],M[8],M[9]);

  #pragma unroll
  for (int c=0;c<4;c++)  z[c] = pz[c];
  #pragma unroll
  for (int c=0;c<10;c++) S[c] = M[c];
}

struct SIn { float4 a[4]; float4 p1[3]; float4 p0[4]; };
__device__ __forceinline__ void s_load(SIn& r, const float* __restrict__ ws1,
                                       const float* __restrict__ ws2, int j, int b){
  const float4* pa = (const float4*)(ws1 + ((size_t)(j+1)*BB + b)*W1S);
  #pragma unroll
  for (int i=0;i<4;i++) r.a[i] = pa[i];
  const float4* q1 = (const float4*)(ws2 + ((size_t)(j+1)*BB + b)*W2S);
  r.p1[0] = q1[1]; r.p1[1] = q1[2]; r.p1[2] = q1[3];
  const float4* q0 = (const float4*)(ws2 + ((size_t)j*BB + b)*W2S);
  r.p0[0] = q0[0]; r.p0[1] = q0[3]; r.p0[2] = q0[4]; r.p0[3] = q0[5];
}

__device__ __forceinline__ void sm_step(const SIn& in, int j, int b,
    float* pzs, float* pss, float* __restrict__ out)
{
  float A1[16]  = {in.a[0].x,in.a[0].y,in.a[0].z,in.a[0].w,
                   in.a[1].x,in.a[1].y,in.a[1].z,in.a[1].w,
                   in.a[2].x,in.a[2].y,in.a[2].z,in.a[2].w,
                   in.a[3].x,in.a[3].y,in.a[3].z,in.a[3].w};
  float Pc1[10] = {in.p1[0].x,in.p1[0].y,in.p1[0].z,in.p1[0].w,
                   in.p1[1].x,in.p1[1].y,in.p1[1].z,in.p1[1].w,
                   in.p1[2].x,in.p1[2].y};
  float pzj[4]  = {in.p0[0].x,in.p0[0].y,in.p0[0].z,in.p0[0].w};
  float Mj[10]  = {in.p0[1].z,in.p0[1].w,
                   in.p0[2].x,in.p0[2].y,in.p0[2].z,in.p0[2].w,
                   in.p0[3].x,in.p0[3].y,in.p0[3].z,in.p0[3].w};

  // zh1 = A_{j+1} * post_z_j  (same fma nesting as the filter's z_hat)
  float zh1[4];
  #pragma unroll
  for (int i=0;i<4;i++)
    zh1[i] = fmaf(A1[i*4+3], pzj[3], fmaf(A1[i*4+2], pzj[2], fmaf(A1[i*4+1], pzj[1], A1[i*4+0]*pzj[0])));

  // D = M_j A_{j+1}^T inv(Pc_{j+1})
  float Pc1f[16]; sym_expand(Pc1, Pc1f);
  float E[16]; inv4(Pc1f, E);
  float Mjf[16]; sym_expand(Mj, Mjf);
  float Bm[16]; mm4_bt(Mjf, A1, Bm);
  float D[16]; mm4(Bm, E, D);

  // z_s = post_z_j + D (pz_s - z_hat_{j+1})
  float dz[4];
  #pragma unroll
  for (int k=0;k<4;k++) dz[k] = pzs[k]-zh1[k];
  float zs[4];
  #pragma unroll
  for (int i=0;i<4;i++)
    zs[i] = pzj[i] + fmaf(D[i*4+3], dz[3], fmaf(D[i*4+2], dz[2], fmaf(D[i*4+1], dz[1], D[i*4+0]*dz[0])));

  // s_s = M_j + D (ps_s - Pc_{j+1}) D^T
  float X[10];
  #pragma unroll
  for (int c=0;c<10;c++) X[c] = pss[c]-Pc1[c];
  float Xf[16]; sym_expand(X, Xf);
  float Y[16]; mm4(D, Xf, Y);
  float Ss[10];
  {
    int c=0;
    #pragma unroll
    for (int i=0;i<4;i++){
      #pragma unroll
      for (int j2=0;j2<4;j2++){
        if (j2 < i) continue;
        float acc = Y[i*4+0]*D[j2*4+0];
        acc = fmaf(Y[i*4+1], D[j2*4+1], acc);
        acc = fmaf(Y[i*4+2], D[j2*4+2], acc);
        acc = fmaf(Y[i*4+3], D[j2*4+3], acc);
        Ss[c] = Mj[c] + acc;
        c++;
      }
    }
  }

  const size_t Z0 = (size_t)BB*TT*DZ;
  *(float4*)(out + ((size_t)b*TT + j)*DZ) = make_float4(zs[0],zs[1],zs[2],zs[3]);
  float Ssf[16]; sym_expand(Ss, Ssf);
  float4* so = (float4*)(out + Z0 + ((size_t)b*TT + j)*16);
  so[0] = make_float4(Ssf[0], Ssf[1], Ssf[2], Ssf[3]);
  so[1] = make_float4(Ssf[4], Ssf[5], Ssf[6], Ssf[7]);
  so[2] = make_float4(Ssf[8], Ssf[9], Ssf[10],Ssf[11]);
  so[3] = make_float4(Ssf[12],Ssf[13],Ssf[14],Ssf[15]);

  #pragma unroll
  for (int c=0;c<4;c++)  pzs[c] = zs[c];
  #pragma unroll
  for (int c=0;c<10;c++) pss[c] = Ss[c];
}

__global__ __launch_bounds__(64) void kvae_seq(
    const float* __restrict__ ws1, float* __restrict__ ws2, float* __restrict__ out)
{
  int b = blockIdx.x*64 + threadIdx.x;

  float z[4] = {0.f,0.f,0.f,0.f};
  float S[10] = {20.f,0.f,0.f,0.f, 20.f,0.f,0.f, 20.f,0.f, 20.f}; // 20*I

  // ---------------- forward filter (double-buffered prefetch) ----------------
  FIn fa, fb;
  f_load(fa, ws1, 0, b);
  for (int t=0; t<TT; t+=2){
    f_load(fb, ws1, t+1, b);            // t+1 <= 255 always
    filt_step(fa, t, b, z, S, ws2);
    if (t+2 < TT) f_load(fa, ws1, t+2, b);
    filt_step(fb, t+1, b, z, S, ws2);
  }

  // output at t = T-1 directly from register state (post_z, post_std)
  const size_t Z0 = (size_t)BB*TT*DZ;
  *(float4*)(out + ((size_t)b*TT + (TT-1))*DZ) = make_float4(z[0],z[1],z[2],z[3]);
  {
    float Sf[16]; sym_expand(S, Sf);
    float4* so = (float4*)(out + Z0 + ((size_t)b*TT + (TT-1))*16);
    so[0] = make_float4(Sf[0], Sf[1], Sf[2], Sf[3]);
    so[1] = make_float4(Sf[4], Sf[5], Sf[6], Sf[7]);
    so[2] = make_float4(Sf[8], Sf[9], Sf[10],Sf[11]);
    so[3] = make_float4(Sf[12],Sf[13],Sf[14],Sf[15]);
  }

  // ---------------- backward smoother (double-buffered prefetch) ----------------
  float pzs[4] = {z[0],z[1],z[2],z[3]};
  float pss[10]; 
  #pragma unroll
  for (int c=0;c<10;c++) pss[c] = S[c];

  SIn sa, sb;
  s_load(sa, ws1, ws2, TT-2, b);
  for (int j=TT-2; j>=0; j-=2){
    if (j >= 1) s_load(sb, ws1, ws2, j-1, b);
    sm_step(sa, j, b, pzs, pss, out);
    if (j >= 2) s_load(sa, ws1, ws2, j-2, b);
    if (j >= 1) sm_step(sb, j-1, b, pzs, pss, out);
  }
}

extern "C" void kernel_launch(void* const* d_in, const int* in_sizes, int n_in,
                              void* d_out, int out_size, void* d_ws, size_t ws_size,
                              hipStream_t stream) {
  const float* a      = (const float*)d_in[0];
  const float* logits = (const float*)d_in[1];
  const float* Abase  = (const float*)d_in[2];
  const float* Cbase  = (const float*)d_in[3];
  float* out = (float*)d_out;
  float* ws  = (float*)d_ws;

  const size_t NT = (size_t)BB*TT;
  float* ws1 = ws;               // 32*NT floats = 67 MB
  float* ws2 = ws1 + (size_t)W1S*NT; // 24*NT floats = 50 MB (total 117 MB)

  kvae_precompute<<<dim3(BB*TT/256), dim3(256), 0, stream>>>(a, logits, Abase, Cbase, ws1);
  kvae_seq<<<dim3(BB/64), dim3(64), 0, stream>>>(ws1, ws2, out);
}

// Round 3
// 458.132 us; speedup vs baseline: 2.1384x; 1.5515x over previous
//
#include <hip/hip_runtime.h>

#define BB 2048
#define TT 256
#define DA 20
#define DZ 4
#define KK 3
#define NC 32      // number of chunks per sequence
#define CL 8       // chunk length (NC*CL == TT)
#define QQ 0.08f   // process noise Q = QQ*I
#define RINV (1.0f/0.03f)

// sym10 layout: [0]=00 [1]=01 [2]=02 [3]=03 [4]=11 [5]=12 [6]=13 [7]=22 [8]=23 [9]=33
__device__ __forceinline__ void sym_expand(const float* s, float* f){
  f[0]=s[0];  f[1]=s[1];  f[2]=s[2];  f[3]=s[3];
  f[4]=s[1];  f[5]=s[4];  f[6]=s[5];  f[7]=s[6];
  f[8]=s[2];  f[9]=s[5];  f[10]=s[7]; f[11]=s[8];
  f[12]=s[3]; f[13]=s[6]; f[14]=s[8]; f[15]=s[9];
}
__device__ __forceinline__ void sym_from_full(const float* F, float* s){
  s[0]=F[0]; s[1]=0.5f*(F[1]+F[4]); s[2]=0.5f*(F[2]+F[8]); s[3]=0.5f*(F[3]+F[12]);
  s[4]=F[5]; s[5]=0.5f*(F[6]+F[9]); s[6]=0.5f*(F[7]+F[13]);
  s[7]=F[10]; s[8]=0.5f*(F[11]+F[14]); s[9]=F[15];
}

__device__ __forceinline__ void inv4(const float* m, float* b){
  float s0 = m[0]*m[5]  - m[4]*m[1];
  float s1 = m[0]*m[6]  - m[4]*m[2];
  float s2 = m[0]*m[7]  - m[4]*m[3];
  float s3 = m[1]*m[6]  - m[5]*m[2];
  float s4 = m[1]*m[7]  - m[5]*m[3];
  float s5 = m[2]*m[7]  - m[6]*m[3];
  float c5 = m[10]*m[15] - m[14]*m[11];
  float c4 = m[9]*m[15]  - m[13]*m[11];
  float c3 = m[9]*m[14]  - m[13]*m[10];
  float c2 = m[8]*m[15]  - m[12]*m[11];
  float c1 = m[8]*m[14]  - m[12]*m[10];
  float c0 = m[8]*m[13]  - m[12]*m[9];
  float det = s0*c5 - s1*c4 + s2*c3 + s3*c2 - s4*c1 + s5*c0;
  float id = 1.0f/det;
  b[0]  = ( m[5]*c5  - m[6]*c4  + m[7]*c3 )*id;
  b[1]  = (-m[1]*c5  + m[2]*c4  - m[3]*c3 )*id;
  b[2]  = ( m[13]*s5 - m[14]*s4 + m[15]*s3)*id;
  b[3]  = (-m[9]*s5  + m[10]*s4 - m[11]*s3)*id;
  b[4]  = (-m[4]*c5  + m[6]*c2  - m[7]*c1 )*id;
  b[5]  = ( m[0]*c5  - m[2]*c2  + m[3]*c1 )*id;
  b[6]  = (-m[12]*s5 + m[14]*s2 - m[15]*s1)*id;
  b[7]  = ( m[8]*s5  - m[10]*s2 + m[11]*s1)*id;
  b[8]  = ( m[4]*c4  - m[5]*c2  + m[7]*c0 )*id;
  b[9]  = (-m[0]*c4  + m[1]*c2  - m[3]*c0 )*id;
  b[10] = ( m[12]*s4 - m[13]*s2 + m[15]*s0)*id;
  b[11] = (-m[8]*s4  + m[9]*s2  - m[11]*s0)*id;
  b[12] = (-m[4]*c3  + m[5]*c1  - m[6]*c0 )*id;
  b[13] = ( m[0]*c3  - m[1]*c1  + m[2]*c0 )*id;
  b[14] = (-m[12]*s3 + m[13]*s1 - m[14]*s0)*id;
  b[15] = ( m[8]*s3  - m[9]*s1  + m[10]*s0)*id;
}

__device__ __forceinline__ void mm4(const float* A, const float* Bm, float* C){
  #pragma unroll
  for (int i=0;i<4;i++){
    #pragma unroll
    for (int j=0;j<4;j++){
      float acc = A[i*4+0]*Bm[0*4+j];
      acc = fmaf(A[i*4+1], Bm[1*4+j], acc);
      acc = fmaf(A[i*4+2], Bm[2*4+j], acc);
      acc = fmaf(A[i*4+3], Bm[3*4+j], acc);
      C[i*4+j] = acc;
    }
  }
}
// C = A * B^T
__device__ __forceinline__ void mm4_bt(const float* A, const float* Bm, float* C){
  #pragma unroll
  for (int i=0;i<4;i++){
    #pragma unroll
    for (int j=0;j<4;j++){
      float acc = A[i*4+0]*Bm[j*4+0];
      acc = fmaf(A[i*4+1], Bm[j*4+1], acc);
      acc = fmaf(A[i*4+2], Bm[j*4+2], acc);
      acc = fmaf(A[i*4+3], Bm[j*4+3], acc);
      C[i*4+j] = acc;
    }
  }
}
// C = A^T * B
__device__ __forceinline__ void mm4_at(const float* A, const float* Bm, float* C){
  #pragma unroll
  for (int i=0;i<4;i++){
    #pragma unroll
    for (int j=0;j<4;j++){
      float acc = A[0*4+i]*Bm[0*4+j];
      acc = fmaf(A[1*4+i], Bm[1*4+j], acc);
      acc = fmaf(A[2*4+i], Bm[2*4+j], acc);
      acc = fmaf(A[3*4+i], Bm[3*4+j], acc);
      C[i*4+j] = acc;
    }
  }
}
__device__ __forceinline__ void mv4(const float* M, const float* v, float* o){
  #pragma unroll
  for (int i=0;i<4;i++)
    o[i] = fmaf(M[i*4+3],v[3],fmaf(M[i*4+2],v[2],fmaf(M[i*4+1],v[1],M[i*4+0]*v[0])));
}
// o = M^T v
__device__ __forceinline__ void mv4_t(const float* M, const float* v, float* o){
  #pragma unroll
  for (int i=0;i<4;i++)
    o[i] = fmaf(M[12+i],v[3],fmaf(M[8+i],v[2],fmaf(M[4+i],v[1],M[i]*v[0])));
}

// mixing: softmax(logits) -> A_mix[16], G = C^T C /R (sym10), w = C^T a /R (4)
__device__ __forceinline__ void mix_build(
    const float* __restrict__ a, const float* __restrict__ logits,
    const float* sA, const float* sC, int b, int t,
    float* Am, float* G, float* w)
{
  const float* lg = logits + ((size_t)b*TT + t)*KK;
  float l0=lg[0], l1=lg[1], l2=lg[2];
  float mx = fmaxf(l0, fmaxf(l1,l2));
  float e0=expf(l0-mx), e1=expf(l1-mx), e2=expf(l2-mx);
  float is = 1.0f/(e0+e1+e2);
  float a0=e0*is, a1=e1*is, a2=e2*is;
  #pragma unroll
  for (int c=0;c<16;c++) Am[c] = fmaf(a0,sA[c],fmaf(a1,sA[16+c],a2*sA[32+c]));
  const float4* af = (const float4*)(a + ((size_t)b*TT+t)*DA);
  float4 v0=af[0],v1=af[1],v2=af[2],v3=af[3],v4=af[4];
  float av[20]={v0.x,v0.y,v0.z,v0.w, v1.x,v1.y,v1.z,v1.w,
                v2.x,v2.y,v2.z,v2.w, v3.x,v3.y,v3.z,v3.w,
                v4.x,v4.y,v4.z,v4.w};
  #pragma unroll
  for (int c=0;c<10;c++) G[c]=0.f;
  w[0]=0.f;w[1]=0.f;w[2]=0.f;w[3]=0.f;
  #pragma unroll
  for (int d=0; d<DA; d++){
    float ad = av[d];
    float c0 = fmaf(a0, sC[d*4+0], fmaf(a1, sC[80+d*4+0], a2*sC[160+d*4+0]));
    float c1 = fmaf(a0, sC[d*4+1], fmaf(a1, sC[80+d*4+1], a2*sC[160+d*4+1]));
    float c2 = fmaf(a0, sC[d*4+2], fmaf(a1, sC[80+d*4+2], a2*sC[160+d*4+2]));
    float c3 = fmaf(a0, sC[d*4+3], fmaf(a1, sC[80+d*4+3], a2*sC[160+d*4+3]));
    w[0]=fmaf(c0,ad,w[0]); w[1]=fmaf(c1,ad,w[1]); w[2]=fmaf(c2,ad,w[2]); w[3]=fmaf(c3,ad,w[3]);
    G[0]=fmaf(c0,c0,G[0]); G[1]=fmaf(c0,c1,G[1]); G[2]=fmaf(c0,c2,G[2]); G[3]=fmaf(c0,c3,G[3]);
    G[4]=fmaf(c1,c1,G[4]); G[5]=fmaf(c1,c2,G[5]); G[6]=fmaf(c1,c3,G[6]);
    G[7]=fmaf(c2,c2,G[7]); G[8]=fmaf(c2,c3,G[8]);
    G[9]=fmaf(c3,c3,G[9]);
  }
  #pragma unroll
  for (int c=0;c<10;c++) G[c]*=RINV;
  #pragma unroll
  for (int c=0;c<4;c++)  w[c]*=RINV;
}

// per-step filter element: Phi=(I+qG)^-1; A*=Phi A; b*=q Phi w; C*=q Phi; eta*=A^T Phi w; J*=A^T Phi G A
__device__ __forceinline__ void elem_build(const float* Am, const float* G, const float* w,
    float* Ae, float* be, float* Ce, float* he, float* Je)
{
  float Gf[16]; sym_expand(G,Gf);
  float N[16];
  #pragma unroll
  for (int i=0;i<16;i++) N[i] = QQ*Gf[i];
  N[0]+=1.f; N[5]+=1.f; N[10]+=1.f; N[15]+=1.f;
  float Phi[16]; inv4(N,Phi);
  mm4(Phi, Am, Ae);
  float Pw[4]; mv4(Phi, w, Pw);
  #pragma unroll
  for (int i=0;i<4;i++) be[i]=QQ*Pw[i];
  mv4_t(Am, Pw, he);
  float PhiG[16]; mm4(Phi, Gf, PhiG);
  float U[16]; mm4_at(Am, PhiG, U);
  float Jf[16]; mm4(U, Am, Jf);
  sym_from_full(Jf, Je);
  float Cf[16];
  #pragma unroll
  for (int i=0;i<16;i++) Cf[i]=QQ*Phi[i];
  sym_from_full(Cf, Ce);
}

// running(earlier) = running ⊗ e(later)
__device__ __forceinline__ void compose(float* Ar, float* br, float* Cr, float* hr, float* Jr,
    const float* Ae, const float* be, const float* Ce, const float* he, const float* Je)
{
  float Crf[16]; sym_expand(Cr,Crf);
  float Jef[16]; sym_expand(Je,Jef);
  float N[16]; mm4(Crf,Jef,N);
  N[0]+=1.f; N[5]+=1.f; N[10]+=1.f; N[15]+=1.f;
  float E[16]; inv4(N,E);
  // A_new = Ae E Ar
  float EA[16]; mm4(E,Ar,EA);
  float Anew[16]; mm4(Ae,EA,Anew);
  // b_new = Ae E (br + Crf he) + be
  float t1[4]; mv4(Crf,he,t1);
  #pragma unroll
  for (int i=0;i<4;i++) t1[i]+=br[i];
  float t2[4]; mv4(E,t1,t2);
  float bnew[4]; mv4(Ae,t2,bnew);
  #pragma unroll
  for (int i=0;i<4;i++) bnew[i]+=be[i];
  // C_new = Ae E Crf Ae^T + Ce
  float EC[16]; mm4(E,Crf,EC);
  float AEC[16]; mm4(Ae,EC,AEC);
  float Cfull[16]; mm4_bt(AEC,Ae,Cfull);
  float Cnew[10]; sym_from_full(Cfull,Cnew);
  #pragma unroll
  for (int i=0;i<10;i++) Cnew[i]+=Ce[i];
  // h_new = Ar^T E^T (he - Jef br) + hr
  float v[4]; mv4(Jef,br,v);
  #pragma unroll
  for (int i=0;i<4;i++) v[i]=he[i]-v[i];
  float Ev[4]; mv4_t(E,v,Ev);
  float hnew[4]; mv4_t(Ar,Ev,hnew);
  #pragma unroll
  for (int i=0;i<4;i++) hnew[i]+=hr[i];
  // J_new = Ar^T E^T Jef Ar + Jr
  float EtJ[16]; mm4_at(E,Jef,EtJ);
  float AtEtJ[16]; mm4_at(Ar,EtJ,AtEtJ);
  float Jfull[16]; mm4(AtEtJ,Ar,Jfull);
  float Jnew[10]; sym_from_full(Jfull,Jnew);
  #pragma unroll
  for (int i=0;i<10;i++) Jnew[i]+=Jr[i];
  #pragma unroll
  for (int i=0;i<16;i++) Ar[i]=Anew[i];
  #pragma unroll
  for (int i=0;i<4;i++){ br[i]=bnew[i]; hr[i]=hnew[i]; }
  #pragma unroll
  for (int i=0;i<10;i++){ Cr[i]=Cnew[i]; Jr[i]=Jnew[i]; }
}

// apply element to state (m,S): m' = A T (m + P eta) + b; P' = A T P A^T + C; T=(I+PJ)^-1
__device__ __forceinline__ void elem_apply(const float* Ae, const float* be, const float* Ce,
    const float* he, const float* Je, float* m, float* S)
{
  float Pf[16]; sym_expand(S,Pf);
  float Jf[16]; sym_expand(Je,Jf);
  float N[16]; mm4(Pf,Jf,N);
  N[0]+=1.f; N[5]+=1.f; N[10]+=1.f; N[15]+=1.f;
  float T[16]; inv4(N,T);
  float t1[4]; mv4(Pf,he,t1);
  #pragma unroll
  for (int i=0;i<4;i++) t1[i]+=m[i];
  float t2[4]; mv4(T,t1,t2);
  float mn[4]; mv4(Ae,t2,mn);
  #pragma unroll
  for (int i=0;i<4;i++) mn[i]+=be[i];
  float TP[16]; mm4(T,Pf,TP);
  float ATP[16]; mm4(Ae,TP,ATP);
  float Pn[16]; mm4_bt(ATP,Ae,Pn);
  float Sn[10]; sym_from_full(Pn,Sn);
  #pragma unroll
  for (int i=0;i<10;i++) S[i]=Sn[i]+Ce[i];
  #pragma unroll
  for (int i=0;i<4;i++) m[i]=mn[i];
}

// smoother per-step: D = Mj A1^T inv(Pc1); e = pzj - D (A1 pzj); F = Mj - D Pc1 D^T
__device__ __forceinline__ void sm_build(const float* A1, const float* Pc1,
    const float* Mj, const float* pzj, float* D, float* e, float* F)
{
  float Pcf[16]; sym_expand(Pc1,Pcf);
  float E[16]; inv4(Pcf,E);
  float Mf[16]; sym_expand(Mj,Mf);
  float MB[16]; mm4_bt(Mf,A1,MB);
  mm4(MB,E,D);
  float zh[4]; mv4(A1,pzj,zh);
  float Dzh[4]; mv4(D,zh,Dzh);
  #pragma unroll
  for (int i=0;i<4;i++) e[i]=pzj[i]-Dzh[i];
  float U[16]; mm4(D,Pcf,U);
  float W[16]; mm4_bt(U,D,W);
  float Ws[10]; sym_from_full(W,Ws);
  #pragma unroll
  for (int i=0;i<10;i++) F[i]=Mj[i]-Ws[i];
}

// record: [0:16]=A [16:26]=Pc [26:30]=pz [30:40]=M (40 floats, 10 float4)
__device__ __forceinline__ void rec_load(const float* __restrict__ rec, int b, int t,
    float* A, float* Pc, float* pz, float* M)
{
  float4 q[10];
  const float4* src = (const float4*)(rec + ((size_t)b*TT+t)*40);
  #pragma unroll
  for (int i=0;i<10;i++) q[i]=src[i];
  const float* f=(const float*)q;
  #pragma unroll
  for (int i=0;i<16;i++) A[i]=f[i];
  #pragma unroll
  for (int i=0;i<10;i++) Pc[i]=f[16+i];
  #pragma unroll
  for (int i=0;i<4;i++) pz[i]=f[26+i];
  #pragma unroll
  for (int i=0;i<10;i++) M[i]=f[30+i];
}

// ================= Kernel A: per-chunk filter element composition =================
__global__ __launch_bounds__(256) void k_fchunk(
    const float* __restrict__ a, const float* __restrict__ logits,
    const float* __restrict__ Abase, const float* __restrict__ Cbase,
    float* __restrict__ chel)
{
  __shared__ float sA[KK*16];
  __shared__ float sC[KK*DA*DZ];
  for (int i=threadIdx.x;i<KK*16;i+=256) sA[i]=Abase[i];
  for (int i=threadIdx.x;i<KK*DA*DZ;i+=256) sC[i]=Cbase[i];
  __syncthreads();
  int tid = blockIdx.x*256+threadIdx.x;
  int c = tid & (NC-1);
  int b = tid >> 5;
  float Ar[16], br[4], Cr[10], hr[4], Jr[10];
  #pragma unroll 1
  for (int s=0;s<CL;s++){
    int t = c*CL+s;
    float Am[16], G[10], w[4];
    mix_build(a,logits,sA,sC,b,t,Am,G,w);
    float Ae[16], be[4], Ce[10], he[4], Je[10];
    elem_build(Am,G,w,Ae,be,Ce,he,Je);
    if (s==0){
      #pragma unroll
      for (int i=0;i<16;i++) Ar[i]=Ae[i];
      #pragma unroll
      for (int i=0;i<4;i++){ br[i]=be[i]; hr[i]=he[i]; }
      #pragma unroll
      for (int i=0;i<10;i++){ Cr[i]=Ce[i]; Jr[i]=Je[i]; }
    } else {
      compose(Ar,br,Cr,hr,Jr,Ae,be,Ce,he,Je);
    }
  }
  float4 buf[11]; float* pb=(float*)buf;
  #pragma unroll
  for (int i=0;i<16;i++) pb[i]=Ar[i];
  #pragma unroll
  for (int i=0;i<4;i++) pb[16+i]=br[i];
  #pragma unroll
  for (int i=0;i<10;i++) pb[20+i]=Cr[i];
  #pragma unroll
  for (int i=0;i<4;i++) pb[30+i]=hr[i];
  #pragma unroll
  for (int i=0;i<10;i++) pb[34+i]=Jr[i];
  float4* d=(float4*)(chel + ((size_t)b*NC+c)*44);
  #pragma unroll
  for (int i=0;i<11;i++) d[i]=buf[i];
}

// ================= Kernel B: sequential scan over chunk boundaries =================
__global__ __launch_bounds__(256) void k_fscan(
    const float* __restrict__ chel, float* __restrict__ fbound)
{
  int b = blockIdx.x*256+threadIdx.x;
  float m[4]={0.f,0.f,0.f,0.f};
  float S[10]={20.f,0.f,0.f,0.f,20.f,0.f,0.f,20.f,0.f,20.f};
  #pragma unroll 1
  for (int c=0;c<NC;c++){
    float4 ob[4]; float* po=(float*)ob;
    #pragma unroll
    for (int i=0;i<4;i++) po[i]=m[i];
    #pragma unroll
    for (int i=0;i<10;i++) po[4+i]=S[i];
    po[14]=0.f; po[15]=0.f;
    float4* d=(float4*)(fbound + ((size_t)b*NC+c)*16);
    #pragma unroll
    for (int i=0;i<4;i++) d[i]=ob[i];
    float4 eb[11];
    const float4* src=(const float4*)(chel + ((size_t)b*NC+c)*44);
    #pragma unroll
    for (int i=0;i<11;i++) eb[i]=src[i];
    const float* pe=(const float*)eb;
    elem_apply(pe, pe+16, pe+20, pe+30, pe+34, m, S);
  }
}

// ================= Kernel C: filter replay within chunks =================
__global__ __launch_bounds__(256) void k_freplay(
    const float* __restrict__ a, const float* __restrict__ logits,
    const float* __restrict__ Abase, const float* __restrict__ Cbase,
    const float* __restrict__ fbound, float* __restrict__ rec)
{
  __shared__ float sA[KK*16];
  __shared__ float sC[KK*DA*DZ];
  for (int i=threadIdx.x;i<KK*16;i+=256) sA[i]=Abase[i];
  for (int i=threadIdx.x;i<KK*DA*DZ;i+=256) sC[i]=Cbase[i];
  __syncthreads();
  int tid = blockIdx.x*256+threadIdx.x;
  int c = tid & (NC-1);
  int b = tid >> 5;
  const float4* fb=(const float4*)(fbound + ((size_t)b*NC+c)*16);
  float4 s0=fb[0],s1=fb[1],s2=fb[2],s3=fb[3];
  float z[4]={s0.x,s0.y,s0.z,s0.w};
  float S[10]={s1.x,s1.y,s1.z,s1.w,s2.x,s2.y,s2.z,s2.w,s3.x,s3.y};
  #pragma unroll 1
  for (int s=0;s<CL;s++){
    int t = c*CL+s;
    float Am[16], G[10], w[4];
    mix_build(a,logits,sA,sC,b,t,Am,G,w);
    float zh[4];
    #pragma unroll
    for (int i=0;i<4;i++)
      zh[i] = fmaf(Am[i*4+3],z[3],fmaf(Am[i*4+2],z[2],fmaf(Am[i*4+1],z[1],Am[i*4+0]*z[0])));
    float Sf[16]; sym_expand(S,Sf);
    float AS[16]; mm4(Am,Sf,AS);
    float P[10];
    {
      int cc=0;
      #pragma unroll
      for (int i=0;i<4;i++){
        #pragma unroll
        for (int j=0;j<4;j++){
          if (j<i) continue;
          float acc = AS[i*4+0]*Am[j*4+0];
          acc = fmaf(AS[i*4+1],Am[j*4+1],acc);
          acc = fmaf(AS[i*4+2],Am[j*4+2],acc);
          acc = fmaf(AS[i*4+3],Am[j*4+3],acc);
          if (i==j) acc += QQ;
          P[cc++] = acc;
        }
      }
    }
    float Pf[16]; sym_expand(P,Pf);
    float Gf[16]; sym_expand(G,Gf);
    float N[16]; mm4(Pf,Gf,N);
    N[0]+=1.f; N[5]+=1.f; N[10]+=1.f; N[15]+=1.f;
    float Ninv[16]; inv4(N,Ninv);
    float Mf[16]; mm4(Ninv,Pf,Mf);
    float M[10]; sym_from_full(Mf,M);
    float u[4];
    #pragma unroll
    for (int i=0;i<4;i++)
      u[i] = w[i] - fmaf(Gf[i*4+3],zh[3],fmaf(Gf[i*4+2],zh[2],fmaf(Gf[i*4+1],zh[1],Gf[i*4+0]*zh[0])));
    float Ms[16]; sym_expand(M,Ms);
    float pz[4];
    #pragma unroll
    for (int i=0;i<4;i++)
      pz[i] = zh[i] + fmaf(Ms[i*4+3],u[3],fmaf(Ms[i*4+2],u[2],fmaf(Ms[i*4+1],u[1],Ms[i*4+0]*u[0])));
    float Pc[10];
    Pc[0]=fmaxf(P[0],1e-4f); Pc[1]=fmaxf(P[1],0.f); Pc[2]=fmaxf(P[2],0.f); Pc[3]=fmaxf(P[3],0.f);
    Pc[4]=fmaxf(P[4],1e-4f); Pc[5]=fmaxf(P[5],0.f); Pc[6]=fmaxf(P[6],0.f);
    Pc[7]=fmaxf(P[7],1e-4f); Pc[8]=fmaxf(P[8],0.f);
    Pc[9]=fmaxf(P[9],1e-4f);
    float4 rb[10]; float* pr=(float*)rb;
    #pragma unroll
    for (int i=0;i<16;i++) pr[i]=Am[i];
    #pragma unroll
    for (int i=0;i<10;i++) pr[16+i]=Pc[i];
    #pragma unroll
    for (int i=0;i<4;i++) pr[26+i]=pz[i];
    #pragma unroll
    for (int i=0;i<10;i++) pr[30+i]=M[i];
    float4* d=(float4*)(rec + ((size_t)b*TT+t)*40);
    #pragma unroll
    for (int i=0;i<10;i++) d[i]=rb[i];
    #pragma unroll
    for (int i=0;i<4;i++) z[i]=pz[i];
    #pragma unroll
    for (int i=0;i<10;i++) S[i]=M[i];
  }
}

// ================= Kernel A2: per-chunk smoother (affine) composition =================
__global__ __launch_bounds__(256) void k_schunk(
    const float* __restrict__ rec, float* __restrict__ smel)
{
  int tid = blockIdx.x*256+threadIdx.x;
  int c = tid & (NC-1);
  int b = tid >> 5;
  int jtop = (c==NC-1) ? (TT-1) : (c*CL+CL);
  float An[16], Pcn[10], pzn[4], Mn[10];
  rec_load(rec,b,jtop,An,Pcn,pzn,Mn);
  float Dr[16], er[4], Fr[10];
  bool first=true;
  #pragma unroll 1
  for (int j=jtop-1; j>=c*CL; --j){
    float Aj[16], Pcj[10], pzj[4], Mj[10];
    rec_load(rec,b,j,Aj,Pcj,pzj,Mj);
    float D[16], e[4], F[10];
    sm_build(An,Pcn,Mj,pzj,D,e,F);
    if (first){
      #pragma unroll
      for (int i=0;i<16;i++) Dr[i]=D[i];
      #pragma unroll
      for (int i=0;i<4;i++) er[i]=e[i];
      #pragma unroll
      for (int i=0;i<10;i++) Fr[i]=F[i];
      first=false;
    } else {
      float Dn[16]; mm4(D,Dr,Dn);
      float t1[4]; mv4(D,er,t1);
      #pragma unroll
      for (int i=0;i<4;i++) er[i]=t1[i]+e[i];
      float Ff[16]; sym_expand(Fr,Ff);
      float U[16]; mm4(D,Ff,U);
      float W[16]; mm4_bt(U,D,W);
      float Ws[10]; sym_from_full(W,Ws);
      #pragma unroll
      for (int i=0;i<10;i++) Fr[i]=Ws[i]+F[i];
      #pragma unroll
      for (int i=0;i<16;i++) Dr[i]=Dn[i];
    }
    #pragma unroll
    for (int i=0;i<16;i++) An[i]=Aj[i];
    #pragma unroll
    for (int i=0;i<10;i++) Pcn[i]=Pcj[i];
  }
  float4 buf[8]; float* pb=(float*)buf;
  #pragma unroll
  for (int i=0;i<16;i++) pb[i]=Dr[i];
  #pragma unroll
  for (int i=0;i<4;i++) pb[16+i]=er[i];
  #pragma unroll
  for (int i=0;i<10;i++) pb[20+i]=Fr[i];
  pb[30]=0.f; pb[31]=0.f;
  float4* d=(float4*)(smel + ((size_t)b*NC+c)*32);
  #pragma unroll
  for (int i=0;i<8;i++) d[i]=buf[i];
}

// ================= Kernel B2: backward scan over chunk boundaries =================
__global__ __launch_bounds__(256) void k_sscan(
    const float* __restrict__ rec, const float* __restrict__ smel, float* __restrict__ sbound)
{
  int b = blockIdx.x*256+threadIdx.x;
  const float4* q=(const float4*)(rec + ((size_t)b*TT+(TT-1))*40);
  float4 q6=q[6],q7=q[7],q8=q[8],q9=q[9];
  float z[4]={q6.z,q6.w,q7.x,q7.y};
  float S[10]={q7.z,q7.w,q8.x,q8.y,q8.z,q8.w,q9.x,q9.y,q9.z,q9.w};
  #pragma unroll 1
  for (int c=NC-1;c>=0;c--){
    float4 ob[4]; float* po=(float*)ob;
    #pragma unroll
    for (int i=0;i<4;i++) po[i]=z[i];
    #pragma unroll
    for (int i=0;i<10;i++) po[4+i]=S[i];
    po[14]=0.f; po[15]=0.f;
    float4* d=(float4*)(sbound + ((size_t)b*NC+c)*16);
    #pragma unroll
    for (int i=0;i<4;i++) d[i]=ob[i];
    float4 eb[8];
    const float4* src=(const float4*)(smel + ((size_t)b*NC+c)*32);
    #pragma unroll
    for (int i=0;i<8;i++) eb[i]=src[i];
    const float* pe=(const float*)eb;
    const float* D=pe; const float* e=pe+16; const float* F=pe+20;
    float zn[4]; mv4(D,z,zn);
    #pragma unroll
    for (int i=0;i<4;i++) zn[i]+=e[i];
    float Sf[16]; sym_expand(S,Sf);
    float U[16]; mm4(D,Sf,U);
    float W[16]; mm4_bt(U,D,W);
    float Sn[10]; sym_from_full(W,Sn);
    #pragma unroll
    for (int i=0;i<10;i++) S[i]=Sn[i]+F[i];
    #pragma unroll
    for (int i=0;i<4;i++) z[i]=zn[i];
  }
}

// ================= Kernel C2: smoother replay within chunks + outputs =================
__global__ __launch_bounds__(256) void k_sreplay(
    const float* __restrict__ rec, const float* __restrict__ sbound, float* __restrict__ out)
{
  int tid = blockIdx.x*256+threadIdx.x;
  int c = tid & (NC-1);
  int b = tid >> 5;
  const size_t Z0 = (size_t)BB*TT*DZ;
  const float4* sb=(const float4*)(sbound + ((size_t)b*NC+c)*16);
  float4 s0=sb[0],s1=sb[1],s2=sb[2],s3=sb[3];
  float z[4]={s0.x,s0.y,s0.z,s0.w};
  float S[10]={s1.x,s1.y,s1.z,s1.w,s2.x,s2.y,s2.z,s2.w,s3.x,s3.y};
  int jtop = (c==NC-1) ? (TT-1) : (c*CL+CL);
  if (c==NC-1){
    *(float4*)(out + ((size_t)b*TT + (TT-1))*DZ) = make_float4(z[0],z[1],z[2],z[3]);
    float Sf[16]; sym_expand(S,Sf);
    float4* so=(float4*)(out + Z0 + ((size_t)b*TT + (TT-1))*16);
    so[0]=make_float4(Sf[0],Sf[1],Sf[2],Sf[3]);
    so[1]=make_float4(Sf[4],Sf[5],Sf[6],Sf[7]);
    so[2]=make_float4(Sf[8],Sf[9],Sf[10],Sf[11]);
    so[3]=make_float4(Sf[12],Sf[13],Sf[14],Sf[15]);
  }
  float An[16], Pcn[10], pzn[4], Mn[10];
  rec_load(rec,b,jtop,An,Pcn,pzn,Mn);
  #pragma unroll 1
  for (int j=jtop-1; j>=c*CL; --j){
    float Aj[16], Pcj[10], pzj[4], Mj[10];
    rec_load(rec,b,j,Aj,Pcj,pzj,Mj);
    float D[16], e[4], F[10];
    sm_build(An,Pcn,Mj,pzj,D,e,F);
    float zn[4]; mv4(D,z,zn);
    #pragma unroll
    for (int i=0;i<4;i++) zn[i]+=e[i];
    float Sf[16]; sym_expand(S,Sf);
    float U[16]; mm4(D,Sf,U);
    float W[16]; mm4_bt(U,D,W);
    float Sn[10]; sym_from_full(W,Sn);
    #pragma unroll
    for (int i=0;i<10;i++) Sn[i]+=F[i];
    *(float4*)(out + ((size_t)b*TT + j)*DZ) = make_float4(zn[0],zn[1],zn[2],zn[3]);
    float Snf[16]; sym_expand(Sn,Snf);
    float4* so=(float4*)(out + Z0 + ((size_t)b*TT + j)*16);
    so[0]=make_float4(Snf[0],Snf[1],Snf[2],Snf[3]);
    so[1]=make_float4(Snf[4],Snf[5],Snf[6],Snf[7]);
    so[2]=make_float4(Snf[8],Snf[9],Snf[10],Snf[11]);
    so[3]=make_float4(Snf[12],Snf[13],Snf[14],Snf[15]);
    #pragma unroll
    for (int i=0;i<4;i++) z[i]=zn[i];
    #pragma unroll
    for (int i=0;i<10;i++) S[i]=Sn[i];
    #pragma unroll
    for (int i=0;i<16;i++) An[i]=Aj[i];
    #pragma unroll
    for (int i=0;i<10;i++) Pcn[i]=Pcj[i];
  }
}

extern "C" void kernel_launch(void* const* d_in, const int* in_sizes, int n_in,
                              void* d_out, int out_size, void* d_ws, size_t ws_size,
                              hipStream_t stream) {
  const float* a      = (const float*)d_in[0];
  const float* logits = (const float*)d_in[1];
  const float* Abase  = (const float*)d_in[2];
  const float* Cbase  = (const float*)d_in[3];
  float* out = (float*)d_out;
  float* ws  = (float*)d_ws;

  const size_t NTT = (size_t)BB*TT;   // 524288
  const size_t NCH = (size_t)BB*NC;   // 65536
  float* rec    = ws;                        // 40*NTT = 20,971,520 floats (83.9 MB)
  float* chel   = rec    + 40*NTT;           // 44*NCH (11.5 MB)
  float* fbound = chel   + 44*NCH;           // 16*NCH (4.2 MB)
  float* smel   = fbound + 16*NCH;           // 32*NCH (8.4 MB)
  float* sbound = smel   + 32*NCH;           // 16*NCH (4.2 MB)  total ~112 MB

  k_fchunk <<<dim3(256), dim3(256), 0, stream>>>(a, logits, Abase, Cbase, chel);
  k_fscan  <<<dim3(BB/256), dim3(256), 0, stream>>>(chel, fbound);
  k_freplay<<<dim3(256), dim3(256), 0, stream>>>(a, logits, Abase, Cbase, fbound, rec);
  k_schunk <<<dim3(256), dim3(256), 0, stream>>>(rec, smel);
  k_sscan  <<<dim3(BB/256), dim3(256), 0, stream>>>(rec, smel, sbound);
  k_sreplay<<<dim3(256), dim3(256), 0, stream>>>(rec, sbound, out);
}

// Round 4
// 293.953 us; speedup vs baseline: 3.3327x; 1.5585x over previous
//
#include <hip/hip_runtime.h>

#define BB 2048
#define TT 256
#define DA 20
#define DZ 4
#define KK 3
#define NC 32      // chunks per sequence
#define CL 8       // chunk length
#define NCH (BB*NC)
#define QQ 0.08f
#define RINV (1.0f/0.03f)

// sym10 layout: [0]=00 [1]=01 [2]=02 [3]=03 [4]=11 [5]=12 [6]=13 [7]=22 [8]=23 [9]=33
__device__ __forceinline__ void sym_expand(const float* s, float* f){
  f[0]=s[0];  f[1]=s[1];  f[2]=s[2];  f[3]=s[3];
  f[4]=s[1];  f[5]=s[4];  f[6]=s[5];  f[7]=s[6];
  f[8]=s[2];  f[9]=s[5];  f[10]=s[7]; f[11]=s[8];
  f[12]=s[3]; f[13]=s[6]; f[14]=s[8]; f[15]=s[9];
}
__device__ __forceinline__ void sym_from_full(const float* F, float* s){
  s[0]=F[0]; s[1]=0.5f*(F[1]+F[4]); s[2]=0.5f*(F[2]+F[8]); s[3]=0.5f*(F[3]+F[12]);
  s[4]=F[5]; s[5]=0.5f*(F[6]+F[9]); s[6]=0.5f*(F[7]+F[13]);
  s[7]=F[10]; s[8]=0.5f*(F[11]+F[14]); s[9]=F[15];
}

__device__ __forceinline__ void inv4(const float* m, float* b){
  float s0 = m[0]*m[5]  - m[4]*m[1];
  float s1 = m[0]*m[6]  - m[4]*m[2];
  float s2 = m[0]*m[7]  - m[4]*m[3];
  float s3 = m[1]*m[6]  - m[5]*m[2];
  float s4 = m[1]*m[7]  - m[5]*m[3];
  float s5 = m[2]*m[7]  - m[6]*m[3];
  float c5 = m[10]*m[15] - m[14]*m[11];
  float c4 = m[9]*m[15]  - m[13]*m[11];
  float c3 = m[9]*m[14]  - m[13]*m[10];
  float c2 = m[8]*m[15]  - m[12]*m[11];
  float c1 = m[8]*m[14]  - m[12]*m[10];
  float c0 = m[8]*m[13]  - m[12]*m[9];
  float det = s0*c5 - s1*c4 + s2*c3 + s3*c2 - s4*c1 + s5*c0;
  float id = 1.0f/det;
  b[0]  = ( m[5]*c5  - m[6]*c4  + m[7]*c3 )*id;
  b[1]  = (-m[1]*c5  + m[2]*c4  - m[3]*c3 )*id;
  b[2]  = ( m[13]*s5 - m[14]*s4 + m[15]*s3)*id;
  b[3]  = (-m[9]*s5  + m[10]*s4 - m[11]*s3)*id;
  b[4]  = (-m[4]*c5  + m[6]*c2  - m[7]*c1 )*id;
  b[5]  = ( m[0]*c5  - m[2]*c2  + m[3]*c1 )*id;
  b[6]  = (-m[12]*s5 + m[14]*s2 - m[15]*s1)*id;
  b[7]  = ( m[8]*s5  - m[10]*s2 + m[11]*s1)*id;
  b[8]  = ( m[4]*c4  - m[5]*c2  + m[7]*c0 )*id;
  b[9]  = (-m[0]*c4  + m[1]*c2  - m[3]*c0 )*id;
  b[10] = ( m[12]*s4 - m[13]*s2 + m[15]*s0)*id;
  b[11] = (-m[8]*s4  + m[9]*s2  - m[11]*s0)*id;
  b[12] = (-m[4]*c3  + m[5]*c1  - m[6]*c0 )*id;
  b[13] = ( m[0]*c3  - m[1]*c1  + m[2]*c0 )*id;
  b[14] = (-m[12]*s3 + m[13]*s1 - m[14]*s0)*id;
  b[15] = ( m[8]*s3  - m[9]*s1  + m[10]*s0)*id;
}

__device__ __forceinline__ void mm4(const float* A, const float* Bm, float* C){
  #pragma unroll
  for (int i=0;i<4;i++){
    #pragma unroll
    for (int j=0;j<4;j++){
      float acc = A[i*4+0]*Bm[0*4+j];
      acc = fmaf(A[i*4+1], Bm[1*4+j], acc);
      acc = fmaf(A[i*4+2], Bm[2*4+j], acc);
      acc = fmaf(A[i*4+3], Bm[3*4+j], acc);
      C[i*4+j] = acc;
    }
  }
}
__device__ __forceinline__ void mm4_bt(const float* A, const float* Bm, float* C){
  #pragma unroll
  for (int i=0;i<4;i++){
    #pragma unroll
    for (int j=0;j<4;j++){
      float acc = A[i*4+0]*Bm[j*4+0];
      acc = fmaf(A[i*4+1], Bm[j*4+1], acc);
      acc = fmaf(A[i*4+2], Bm[j*4+2], acc);
      acc = fmaf(A[i*4+3], Bm[j*4+3], acc);
      C[i*4+j] = acc;
    }
  }
}
__device__ __forceinline__ void mm4_at(const float* A, const float* Bm, float* C){
  #pragma unroll
  for (int i=0;i<4;i++){
    #pragma unroll
    for (int j=0;j<4;j++){
      float acc = A[0*4+i]*Bm[0*4+j];
      acc = fmaf(A[1*4+i], Bm[1*4+j], acc);
      acc = fmaf(A[2*4+i], Bm[2*4+j], acc);
      acc = fmaf(A[3*4+i], Bm[3*4+j], acc);
      C[i*4+j] = acc;
    }
  }
}
__device__ __forceinline__ void mv4(const float* M, const float* v, float* o){
  #pragma unroll
  for (int i=0;i<4;i++)
    o[i] = fmaf(M[i*4+3],v[3],fmaf(M[i*4+2],v[2],fmaf(M[i*4+1],v[1],M[i*4+0]*v[0])));
}
__device__ __forceinline__ void mv4_t(const float* M, const float* v, float* o){
  #pragma unroll
  for (int i=0;i<4;i++)
    o[i] = fmaf(M[12+i],v[3],fmaf(M[8+i],v[2],fmaf(M[4+i],v[1],M[i]*v[0])));
}

// plane index: buffers are float4 planes [p][c][b] -> coalesced over b (lane dim)
__device__ __forceinline__ size_t PIDX(int p, int c, int b){
  return ((size_t)p*NC + c)*BB + b;
}

// mixing: softmax(logits) -> A_mix[16], G = C^T C /R (sym10), w = C^T a /R (4)
__device__ __forceinline__ void mix_build(
    const float* __restrict__ a, const float* __restrict__ logits,
    const float* sA, const float* sC, int b, int t,
    float* Am, float* G, float* w)
{
  const float* lg = logits + ((size_t)b*TT + t)*KK;
  float l0=lg[0], l1=lg[1], l2=lg[2];
  float mx = fmaxf(l0, fmaxf(l1,l2));
  float e0=expf(l0-mx), e1=expf(l1-mx), e2=expf(l2-mx);
  float is = 1.0f/(e0+e1+e2);
  float a0=e0*is, a1=e1*is, a2=e2*is;
  #pragma unroll
  for (int c=0;c<16;c++) Am[c] = fmaf(a0,sA[c],fmaf(a1,sA[16+c],a2*sA[32+c]));
  const float4* af = (const float4*)(a + ((size_t)b*TT+t)*DA);
  float4 v0=af[0],v1=af[1],v2=af[2],v3=af[3],v4=af[4];
  float av[20]={v0.x,v0.y,v0.z,v0.w, v1.x,v1.y,v1.z,v1.w,
                v2.x,v2.y,v2.z,v2.w, v3.x,v3.y,v3.z,v3.w,
                v4.x,v4.y,v4.z,v4.w};
  #pragma unroll
  for (int c=0;c<10;c++) G[c]=0.f;
  w[0]=0.f;w[1]=0.f;w[2]=0.f;w[3]=0.f;
  #pragma unroll
  for (int d=0; d<DA; d++){
    float ad = av[d];
    float c0 = fmaf(a0, sC[d*4+0], fmaf(a1, sC[80+d*4+0], a2*sC[160+d*4+0]));
    float c1 = fmaf(a0, sC[d*4+1], fmaf(a1, sC[80+d*4+1], a2*sC[160+d*4+1]));
    float c2 = fmaf(a0, sC[d*4+2], fmaf(a1, sC[80+d*4+2], a2*sC[160+d*4+2]));
    float c3 = fmaf(a0, sC[d*4+3], fmaf(a1, sC[80+d*4+3], a2*sC[160+d*4+3]));
    w[0]=fmaf(c0,ad,w[0]); w[1]=fmaf(c1,ad,w[1]); w[2]=fmaf(c2,ad,w[2]); w[3]=fmaf(c3,ad,w[3]);
    G[0]=fmaf(c0,c0,G[0]); G[1]=fmaf(c0,c1,G[1]); G[2]=fmaf(c0,c2,G[2]); G[3]=fmaf(c0,c3,G[3]);
    G[4]=fmaf(c1,c1,G[4]); G[5]=fmaf(c1,c2,G[5]); G[6]=fmaf(c1,c3,G[6]);
    G[7]=fmaf(c2,c2,G[7]); G[8]=fmaf(c2,c3,G[8]);
    G[9]=fmaf(c3,c3,G[9]);
  }
  #pragma unroll
  for (int c=0;c<10;c++) G[c]*=RINV;
  #pragma unroll
  for (int c=0;c<4;c++)  w[c]*=RINV;
}

// filter element: Phi=(I+qG)^-1; A*=Phi A; b*=q Phi w; C*=q Phi; eta*=A^T Phi w; J*=A^T Phi G A
__device__ __forceinline__ void elem_build(const float* Am, const float* G, const float* w,
    float* Ae, float* be, float* Ce, float* he, float* Je)
{
  float Gf[16]; sym_expand(G,Gf);
  float N[16];
  #pragma unroll
  for (int i=0;i<16;i++) N[i] = QQ*Gf[i];
  N[0]+=1.f; N[5]+=1.f; N[10]+=1.f; N[15]+=1.f;
  float Phi[16]; inv4(N,Phi);
  mm4(Phi, Am, Ae);
  float Pw[4]; mv4(Phi, w, Pw);
  #pragma unroll
  for (int i=0;i<4;i++) be[i]=QQ*Pw[i];
  mv4_t(Am, Pw, he);
  float PhiG[16]; mm4(Phi, Gf, PhiG);
  float U[16]; mm4_at(Am, PhiG, U);
  float Jf[16]; mm4(U, Am, Jf);
  sym_from_full(Jf, Je);
  float Cf[16];
  #pragma unroll
  for (int i=0;i<16;i++) Cf[i]=QQ*Phi[i];
  sym_from_full(Cf, Ce);
}

// running(earlier) = running ⊗ e(later)
__device__ __forceinline__ void compose(float* Ar, float* br, float* Cr, float* hr, float* Jr,
    const float* Ae, const float* be, const float* Ce, const float* he, const float* Je)
{
  float Crf[16]; sym_expand(Cr,Crf);
  float Jef[16]; sym_expand(Je,Jef);
  float N[16]; mm4(Crf,Jef,N);
  N[0]+=1.f; N[5]+=1.f; N[10]+=1.f; N[15]+=1.f;
  float E[16]; inv4(N,E);
  float EA[16]; mm4(E,Ar,EA);
  float Anew[16]; mm4(Ae,EA,Anew);
  float t1[4]; mv4(Crf,hr ? he : he,t1); // t1 = Crf*he
  #pragma unroll
  for (int i=0;i<4;i++) t1[i]+=br[i];
  float t2[4]; mv4(E,t1,t2);
  float bnew[4]; mv4(Ae,t2,bnew);
  #pragma unroll
  for (int i=0;i<4;i++) bnew[i]+=be[i];
  float EC[16]; mm4(E,Crf,EC);
  float AEC[16]; mm4(Ae,EC,AEC);
  float Cfull[16]; mm4_bt(AEC,Ae,Cfull);
  float Cnew[10]; sym_from_full(Cfull,Cnew);
  #pragma unroll
  for (int i=0;i<10;i++) Cnew[i]+=Ce[i];
  float v[4]; mv4(Jef,br,v);
  #pragma unroll
  for (int i=0;i<4;i++) v[i]=he[i]-v[i];
  float Ev[4]; mv4_t(E,v,Ev);
  float hnew[4]; mv4_t(Ar,Ev,hnew);
  #pragma unroll
  for (int i=0;i<4;i++) hnew[i]+=hr[i];
  float EtJ[16]; mm4_at(E,Jef,EtJ);
  float AtEtJ[16]; mm4_at(Ar,EtJ,AtEtJ);
  float Jfull[16]; mm4(AtEtJ,Ar,Jfull);
  float Jnew[10]; sym_from_full(Jfull,Jnew);
  #pragma unroll
  for (int i=0;i<10;i++) Jnew[i]+=Jr[i];
  #pragma unroll
  for (int i=0;i<16;i++) Ar[i]=Anew[i];
  #pragma unroll
  for (int i=0;i<4;i++){ br[i]=bnew[i]; hr[i]=hnew[i]; }
  #pragma unroll
  for (int i=0;i<10;i++){ Cr[i]=Cnew[i]; Jr[i]=Jnew[i]; }
}

// apply element to state (m,S)
__device__ __forceinline__ void elem_apply(const float* Ae, const float* be, const float* Ce,
    const float* he, const float* Je, float* m, float* S)
{
  float Pf[16]; sym_expand(S,Pf);
  float Jf[16]; sym_expand(Je,Jf);
  float N[16]; mm4(Pf,Jf,N);
  N[0]+=1.f; N[5]+=1.f; N[10]+=1.f; N[15]+=1.f;
  float T[16]; inv4(N,T);
  float t1[4]; mv4(Pf,he,t1);
  #pragma unroll
  for (int i=0;i<4;i++) t1[i]+=m[i];
  float t2[4]; mv4(T,t1,t2);
  float mn[4]; mv4(Ae,t2,mn);
  #pragma unroll
  for (int i=0;i<4;i++) mn[i]+=be[i];
  float TP[16]; mm4(T,Pf,TP);
  float ATP[16]; mm4(Ae,TP,ATP);
  float Pn[16]; mm4_bt(ATP,Ae,Pn);
  float Sn[10]; sym_from_full(Pn,Sn);
  #pragma unroll
  for (int i=0;i<10;i++) S[i]=Sn[i]+Ce[i];
  #pragma unroll
  for (int i=0;i<4;i++) m[i]=mn[i];
}

// smoother per-step element: D = Mj A1^T inv(Pc1); e = pzj - D (A1 pzj); F = Mj - D Pc1 D^T
__device__ __forceinline__ void sm_build(const float* A1, const float* Pc1,
    const float* Mj, const float* pzj, float* D, float* e, float* F)
{
  float Pcf[16]; sym_expand(Pc1,Pcf);
  float E[16]; inv4(Pcf,E);
  float Mf[16]; sym_expand(Mj,Mf);
  float MB[16]; mm4_bt(Mf,A1,MB);
  mm4(MB,E,D);
  float zh[4]; mv4(A1,pzj,zh);
  float Dzh[4]; mv4(D,zh,Dzh);
  #pragma unroll
  for (int i=0;i<4;i++) e[i]=pzj[i]-Dzh[i];
  float U[16]; mm4(D,Pcf,U);
  float W[16]; mm4_bt(U,D,W);
  float Ws[10]; sym_from_full(W,Ws);
  #pragma unroll
  for (int i=0;i<10;i++) F[i]=Mj[i]-Ws[i];
}

// apply smoother element: z' = D z + e; S' = D S D^T + F
__device__ __forceinline__ void sm_apply(const float* D, const float* e, const float* F,
    float* z, float* S)
{
  float zn[4]; mv4(D,z,zn);
  #pragma unroll
  for (int i=0;i<4;i++) z[i]=zn[i]+e[i];
  float Sf[16]; sym_expand(S,Sf);
  float U[16]; mm4(D,Sf,U);
  float W[16]; mm4_bt(U,D,W);
  float Sn[10]; sym_from_full(W,Sn);
  #pragma unroll
  for (int i=0;i<10;i++) S[i]=Sn[i]+F[i];
}

// ================= Kernel 1: per-chunk filter element composition =================
__global__ __launch_bounds__(256) void k_fchunk(
    const float* __restrict__ a, const float* __restrict__ logits,
    const float* __restrict__ Abase, const float* __restrict__ Cbase,
    float4* __restrict__ chel)
{
  __shared__ float sA[KK*16];
  __shared__ float sC[KK*DA*DZ];
  for (int i=threadIdx.x;i<KK*16;i+=256) sA[i]=Abase[i];
  for (int i=threadIdx.x;i<KK*DA*DZ;i+=256) sC[i]=Cbase[i];
  __syncthreads();
  int tid = blockIdx.x*256+threadIdx.x;
  int b = tid & (BB-1);
  int c = tid >> 11;
  float Ar[16], br[4], Cr[10], hr[4], Jr[10];
  #pragma unroll 1
  for (int s=0;s<CL;s++){
    int t = c*CL+s;
    float Am[16], G[10], w[4];
    mix_build(a,logits,sA,sC,b,t,Am,G,w);
    float Ae[16], be[4], Ce[10], he[4], Je[10];
    elem_build(Am,G,w,Ae,be,Ce,he,Je);
    if (s==0){
      #pragma unroll
      for (int i=0;i<16;i++) Ar[i]=Ae[i];
      #pragma unroll
      for (int i=0;i<4;i++){ br[i]=be[i]; hr[i]=he[i]; }
      #pragma unroll
      for (int i=0;i<10;i++){ Cr[i]=Ce[i]; Jr[i]=Je[i]; }
    } else {
      compose(Ar,br,Cr,hr,Jr,Ae,be,Ce,he,Je);
    }
  }
  float4 buf[11]; float* pb=(float*)buf;
  #pragma unroll
  for (int i=0;i<16;i++) pb[i]=Ar[i];
  #pragma unroll
  for (int i=0;i<4;i++) pb[16+i]=br[i];
  #pragma unroll
  for (int i=0;i<10;i++) pb[20+i]=Cr[i];
  #pragma unroll
  for (int i=0;i<4;i++) pb[30+i]=hr[i];
  #pragma unroll
  for (int i=0;i<10;i++) pb[34+i]=Jr[i];
  #pragma unroll
  for (int p=0;p<11;p++) chel[PIDX(p,c,b)] = buf[p];
}

// ================= Kernel 2: sequential scan over chunk boundaries (filter) =================
__global__ __launch_bounds__(256) void k_fscan(
    const float4* __restrict__ chel, float4* __restrict__ fbound)
{
  int b = blockIdx.x*256+threadIdx.x;
  float m[4]={0.f,0.f,0.f,0.f};
  float S[10]={20.f,0.f,0.f,0.f,20.f,0.f,0.f,20.f,0.f,20.f};
  float4 cur[11], nxt[11];
  #pragma unroll
  for (int p=0;p<11;p++) cur[p]=chel[PIDX(p,0,b)];
  #pragma unroll 1
  for (int c=0;c<NC;c++){
    float4 ob[4]; float* po=(float*)ob;
    #pragma unroll
    for (int i=0;i<4;i++) po[i]=m[i];
    #pragma unroll
    for (int i=0;i<10;i++) po[4+i]=S[i];
    po[14]=0.f; po[15]=0.f;
    #pragma unroll
    for (int p=0;p<4;p++) fbound[PIDX(p,c,b)] = ob[p];
    if (c+1<NC){
      #pragma unroll
      for (int p=0;p<11;p++) nxt[p]=chel[PIDX(p,c+1,b)];
    }
    const float* pe=(const float*)cur;
    elem_apply(pe, pe+16, pe+20, pe+30, pe+34, m, S);
    #pragma unroll
    for (int p=0;p<11;p++) cur[p]=nxt[p];
  }
}

// ================= Kernel 3: filter replay + smoother element emission =================
// el slot layout: slot k (k=0..7) holds E_{c*8+k}: D[16], e[4], F[10], pad2 (8 float4 planes)
__global__ __launch_bounds__(256) void k_freplay(
    const float* __restrict__ a, const float* __restrict__ logits,
    const float* __restrict__ Abase, const float* __restrict__ Cbase,
    const float4* __restrict__ fbound,
    float4* __restrict__ el, float4* __restrict__ bF0, float4* __restrict__ bL7)
{
  __shared__ float sA[KK*16];
  __shared__ float sC[KK*DA*DZ];
  for (int i=threadIdx.x;i<KK*16;i+=256) sA[i]=Abase[i];
  for (int i=threadIdx.x;i<KK*DA*DZ;i+=256) sC[i]=Cbase[i];
  __syncthreads();
  int tid = blockIdx.x*256+threadIdx.x;
  int b = tid & (BB-1);
  int c = tid >> 11;
  float4 fb[4];
  #pragma unroll
  for (int p=0;p<4;p++) fb[p]=fbound[PIDX(p,c,b)];
  const float* pf=(const float*)fb;
  float z[4]={pf[0],pf[1],pf[2],pf[3]};
  float S[10]={pf[4],pf[5],pf[6],pf[7],pf[8],pf[9],pf[10],pf[11],pf[12],pf[13]};
  float Mprev[10], pzprev[4];
  #pragma unroll 1
  for (int s=0;s<CL;s++){
    int t = c*CL+s;
    float Am[16], G[10], w[4];
    mix_build(a,logits,sA,sC,b,t,Am,G,w);
    float zh[4];
    mv4(Am,z,zh);
    float Sf[16]; sym_expand(S,Sf);
    float AS[16]; mm4(Am,Sf,AS);
    float P[10];
    {
      int cc=0;
      #pragma unroll
      for (int i=0;i<4;i++){
        #pragma unroll
        for (int j=0;j<4;j++){
          if (j<i) continue;
          float acc = AS[i*4+0]*Am[j*4+0];
          acc = fmaf(AS[i*4+1],Am[j*4+1],acc);
          acc = fmaf(AS[i*4+2],Am[j*4+2],acc);
          acc = fmaf(AS[i*4+3],Am[j*4+3],acc);
          if (i==j) acc += QQ;
          P[cc++] = acc;
        }
      }
    }
    float Pf[16]; sym_expand(P,Pf);
    float Gf[16]; sym_expand(G,Gf);
    float N[16]; mm4(Pf,Gf,N);
    N[0]+=1.f; N[5]+=1.f; N[10]+=1.f; N[15]+=1.f;
    float Ninv[16]; inv4(N,Ninv);
    float Mf[16]; mm4(Ninv,Pf,Mf);
    float M[10]; sym_from_full(Mf,M);
    float u[4];
    #pragma unroll
    for (int i=0;i<4;i++)
      u[i] = w[i] - fmaf(Gf[i*4+3],zh[3],fmaf(Gf[i*4+2],zh[2],fmaf(Gf[i*4+1],zh[1],Gf[i*4+0]*zh[0])));
    float Ms[16]; sym_expand(M,Ms);
    float pz[4];
    #pragma unroll
    for (int i=0;i<4;i++)
      pz[i] = zh[i] + fmaf(Ms[i*4+3],u[3],fmaf(Ms[i*4+2],u[2],fmaf(Ms[i*4+1],u[1],Ms[i*4+0]*u[0])));
    float Pc[10];
    Pc[0]=fmaxf(P[0],1e-4f); Pc[1]=fmaxf(P[1],0.f); Pc[2]=fmaxf(P[2],0.f); Pc[3]=fmaxf(P[3],0.f);
    Pc[4]=fmaxf(P[4],1e-4f); Pc[5]=fmaxf(P[5],0.f); Pc[6]=fmaxf(P[6],0.f);
    Pc[7]=fmaxf(P[7],1e-4f); Pc[8]=fmaxf(P[8],0.f);
    Pc[9]=fmaxf(P[9],1e-4f);

    if (s==0){
      // stash chunk-first A, Pc for boundary element of chunk c-1
      float4 f0[7]; float* p0=(float*)f0;
      #pragma unroll
      for (int i=0;i<16;i++) p0[i]=Am[i];
      #pragma unroll
      for (int i=0;i<10;i++) p0[16+i]=Pc[i];
      p0[26]=0.f; p0[27]=0.f;
      #pragma unroll
      for (int p=0;p<7;p++) bF0[PIDX(p,c,b)] = f0[p];
    } else {
      // smoother element E_{t-1} from (Mprev, pzprev) and current (Am, Pc)
      float D[16], e[4], F[10];
      sm_build(Am, Pc, Mprev, pzprev, D, e, F);
      float4 eb[8]; float* pe2=(float*)eb;
      #pragma unroll
      for (int i=0;i<16;i++) pe2[i]=D[i];
      #pragma unroll
      for (int i=0;i<4;i++) pe2[16+i]=e[i];
      #pragma unroll
      for (int i=0;i<10;i++) pe2[20+i]=F[i];
      pe2[30]=0.f; pe2[31]=0.f;
      int slot = s-1;
      #pragma unroll
      for (int p=0;p<8;p++) el[PIDX(slot*8+p,c,b)] = eb[p];
    }
    #pragma unroll
    for (int i=0;i<10;i++) Mprev[i]=M[i];
    #pragma unroll
    for (int i=0;i<4;i++) pzprev[i]=pz[i];
    #pragma unroll
    for (int i=0;i<4;i++) z[i]=pz[i];
    #pragma unroll
    for (int i=0;i<10;i++) S[i]=M[i];
  }
  // chunk-last posterior (M7, pz7)
  float4 l7[4]; float* pl=(float*)l7;
  #pragma unroll
  for (int i=0;i<10;i++) pl[i]=Mprev[i];
  #pragma unroll
  for (int i=0;i<4;i++) pl[10+i]=pzprev[i];
  pl[14]=0.f; pl[15]=0.f;
  #pragma unroll
  for (int p=0;p<4;p++) bL7[PIDX(p,c,b)] = l7[p];
}

// ================= Kernel 4: per-chunk smoother composition (+ boundary element) =================
__global__ __launch_bounds__(256) void k_schunk(
    float4* __restrict__ el, const float4* __restrict__ bF0, const float4* __restrict__ bL7,
    float4* __restrict__ smel)
{
  int tid = blockIdx.x*256+threadIdx.x;
  int b = tid & (BB-1);
  int c = tid >> 11;
  float Dr[16], er[4], Fr[10];
  int kstart;
  if (c < NC-1){
    // boundary element E_{c*8+7}: needs (M7,pz7) of chunk c and (A0,Pc0) of chunk c+1
    float4 l7[4];
    #pragma unroll
    for (int p=0;p<4;p++) l7[p]=bL7[PIDX(p,c,b)];
    const float* pl=(const float*)l7;
    float M7[10]={pl[0],pl[1],pl[2],pl[3],pl[4],pl[5],pl[6],pl[7],pl[8],pl[9]};
    float pz7[4]={pl[10],pl[11],pl[12],pl[13]};
    float4 f0[7];
    #pragma unroll
    for (int p=0;p<7;p++) f0[p]=bF0[PIDX(p,c+1,b)];
    const float* p0=(const float*)f0;
    float A0[16]; 
    #pragma unroll
    for (int i=0;i<16;i++) A0[i]=p0[i];
    float Pc0[10];
    #pragma unroll
    for (int i=0;i<10;i++) Pc0[i]=p0[16+i];
    sm_build(A0,Pc0,M7,pz7,Dr,er,Fr);
    // store as el slot 7 for k_sreplay
    float4 eb[8]; float* pe2=(float*)eb;
    #pragma unroll
    for (int i=0;i<16;i++) pe2[i]=Dr[i];
    #pragma unroll
    for (int i=0;i<4;i++) pe2[16+i]=er[i];
    #pragma unroll
    for (int i=0;i<10;i++) pe2[20+i]=Fr[i];
    pe2[30]=0.f; pe2[31]=0.f;
    #pragma unroll
    for (int p=0;p<8;p++) el[PIDX(7*8+p,c,b)] = eb[p];
    kstart = 6;
  } else {
    // chunk 31: start from slot 6 (j=254)
    float4 eb[8];
    #pragma unroll
    for (int p=0;p<8;p++) eb[p]=el[PIDX(6*8+p,c,b)];
    const float* pe=(const float*)eb;
    #pragma unroll
    for (int i=0;i<16;i++) Dr[i]=pe[i];
    #pragma unroll
    for (int i=0;i<4;i++) er[i]=pe[16+i];
    #pragma unroll
    for (int i=0;i<10;i++) Fr[i]=pe[20+i];
    kstart = 5;
  }
  #pragma unroll 1
  for (int k=kstart;k>=0;k--){
    float4 eb[8];
    #pragma unroll
    for (int p=0;p<8;p++) eb[p]=el[PIDX(k*8+p,c,b)];
    const float* pe=(const float*)eb;
    const float* D=pe; const float* e=pe+16; const float* F=pe+20;
    // running = E_k ∘ running
    float Dn[16]; mm4(D,Dr,Dn);
    float t1[4]; mv4(D,er,t1);
    #pragma unroll
    for (int i=0;i<4;i++) er[i]=t1[i]+e[i];
    float Ff[16]; sym_expand(Fr,Ff);
    float U[16]; mm4(D,Ff,U);
    float W[16]; mm4_bt(U,D,W);
    float Ws[10]; sym_from_full(W,Ws);
    #pragma unroll
    for (int i=0;i<10;i++) Fr[i]=Ws[i]+F[i];
    #pragma unroll
    for (int i=0;i<16;i++) Dr[i]=Dn[i];
  }
  float4 ob[8]; float* po=(float*)ob;
  #pragma unroll
  for (int i=0;i<16;i++) po[i]=Dr[i];
  #pragma unroll
  for (int i=0;i<4;i++) po[16+i]=er[i];
  #pragma unroll
  for (int i=0;i<10;i++) po[20+i]=Fr[i];
  po[30]=0.f; po[31]=0.f;
  #pragma unroll
  for (int p=0;p<8;p++) smel[PIDX(p,c,b)] = ob[p];
}

// ================= Kernel 5: backward scan over chunk boundaries (smoother) =================
__global__ __launch_bounds__(256) void k_sscan(
    const float4* __restrict__ smel, const float4* __restrict__ bL7,
    float4* __restrict__ sbound)
{
  int b = blockIdx.x*256+threadIdx.x;
  // terminal smoothed state = filter posterior at t=255 = (pz7, M7) of chunk 31
  float4 l7[4];
  #pragma unroll
  for (int p=0;p<4;p++) l7[p]=bL7[PIDX(p,NC-1,b)];
  const float* pl=(const float*)l7;
  float S[10]={pl[0],pl[1],pl[2],pl[3],pl[4],pl[5],pl[6],pl[7],pl[8],pl[9]};
  float z[4]={pl[10],pl[11],pl[12],pl[13]};
  float4 cur[8], nxt[8];
  #pragma unroll
  for (int p=0;p<8;p++) cur[p]=smel[PIDX(p,NC-1,b)];
  #pragma unroll 1
  for (int c=NC-1;c>=0;c--){
    float4 ob[4]; float* po=(float*)ob;
    #pragma unroll
    for (int i=0;i<4;i++) po[i]=z[i];
    #pragma unroll
    for (int i=0;i<10;i++) po[4+i]=S[i];
    po[14]=0.f; po[15]=0.f;
    #pragma unroll
    for (int p=0;p<4;p++) sbound[PIDX(p,c,b)] = ob[p];
    if (c>0){
      #pragma unroll
      for (int p=0;p<8;p++) nxt[p]=smel[PIDX(p,c-1,b)];
    }
    const float* pe=(const float*)cur;
    sm_apply(pe, pe+16, pe+20, z, S);
    #pragma unroll
    for (int p=0;p<8;p++) cur[p]=nxt[p];
  }
}

// ================= Kernel 6: smoother replay within chunks + outputs =================
__global__ __launch_bounds__(256) void k_sreplay(
    const float4* __restrict__ el, const float4* __restrict__ sbound,
    float* __restrict__ out)
{
  int tid = blockIdx.x*256+threadIdx.x;
  int b = tid & (BB-1);
  int c = tid >> 11;
  const size_t Z0 = (size_t)BB*TT*DZ;
  float4 sb[4];
  #pragma unroll
  for (int p=0;p<4;p++) sb[p]=sbound[PIDX(p,c,b)];
  const float* ps=(const float*)sb;
  float z[4]={ps[0],ps[1],ps[2],ps[3]};
  float S[10]={ps[4],ps[5],ps[6],ps[7],ps[8],ps[9],ps[10],ps[11],ps[12],ps[13]};
  int ktop;
  if (c==NC-1){
    // terminal output at j=255
    *(float4*)(out + ((size_t)b*TT + (TT-1))*DZ) = make_float4(z[0],z[1],z[2],z[3]);
    float Sf[16]; sym_expand(S,Sf);
    float4* so=(float4*)(out + Z0 + ((size_t)b*TT + (TT-1))*16);
    so[0]=make_float4(Sf[0],Sf[1],Sf[2],Sf[3]);
    so[1]=make_float4(Sf[4],Sf[5],Sf[6],Sf[7]);
    so[2]=make_float4(Sf[8],Sf[9],Sf[10],Sf[11]);
    so[3]=make_float4(Sf[12],Sf[13],Sf[14],Sf[15]);
    ktop = 6;
  } else {
    ktop = 7;
  }
  #pragma unroll 1
  for (int k=ktop;k>=0;k--){
    float4 eb[8];
    #pragma unroll
    for (int p=0;p<8;p++) eb[p]=el[PIDX(k*8+p,c,b)];
    const float* pe=(const float*)eb;
    sm_apply(pe, pe+16, pe+20, z, S);
    int j = c*CL + k;
    *(float4*)(out + ((size_t)b*TT + j)*DZ) = make_float4(z[0],z[1],z[2],z[3]);
    float Sf[16]; sym_expand(S,Sf);
    float4* so=(float4*)(out + Z0 + ((size_t)b*TT + j)*16);
    so[0]=make_float4(Sf[0],Sf[1],Sf[2],Sf[3]);
    so[1]=make_float4(Sf[4],Sf[5],Sf[6],Sf[7]);
    so[2]=make_float4(Sf[8],Sf[9],Sf[10],Sf[11]);
    so[3]=make_float4(Sf[12],Sf[13],Sf[14],Sf[15]);
  }
}

extern "C" void kernel_launch(void* const* d_in, const int* in_sizes, int n_in,
                              void* d_out, int out_size, void* d_ws, size_t ws_size,
                              hipStream_t stream) {
  const float* a      = (const float*)d_in[0];
  const float* logits = (const float*)d_in[1];
  const float* Abase  = (const float*)d_in[2];
  const float* Cbase  = (const float*)d_in[3];
  float* out = (float*)d_out;

  float4* ws4 = (float4*)d_ws;
  float4* chel   = ws4;                         // 11 planes
  float4* fbound = chel   + (size_t)11*NCH;     // 4 planes
  float4* el     = fbound + (size_t)4*NCH;      // 64 planes (8 slots x 8)
  float4* bF0    = el     + (size_t)64*NCH;     // 7 planes
  float4* bL7    = bF0    + (size_t)7*NCH;      // 4 planes
  float4* smel   = bL7    + (size_t)4*NCH;      // 8 planes
  float4* sbound = smel   + (size_t)8*NCH;      // 4 planes  (total 102 planes = 107 MB)

  k_fchunk <<<dim3(NCH/256), dim3(256), 0, stream>>>(a, logits, Abase, Cbase, chel);
  k_fscan  <<<dim3(BB/256), dim3(256), 0, stream>>>(chel, fbound);
  k_freplay<<<dim3(NCH/256), dim3(256), 0, stream>>>(a, logits, Abase, Cbase, fbound, el, bF0, bL7);
  k_schunk <<<dim3(NCH/256), dim3(256), 0, stream>>>(el, bF0, bL7, smel);
  k_sscan  <<<dim3(BB/256), dim3(256), 0, stream>>>(smel, bL7, sbound);
  k_sreplay<<<dim3(NCH/256), dim3(256), 0, stream>>>(el, sbound, out);
}